// Round 6
// baseline (3599.405 us; speedup 1.0000x reference)
//
#include <hip/hip_runtime.h>

typedef __attribute__((ext_vector_type(8))) short bf16x8;
typedef __attribute__((ext_vector_type(4))) float f32x4;

#define MFMA16(a,b,c) __builtin_amdgcn_mfma_f32_16x16x32_bf16((a),(b),(c),0,0,0)

#define T_SEQ  720
#define NB     512
#define HD     128
#define GD     512
#define BT     16
#define HP     136   // h row stride: 68 words % 32 banks = 4 -> 2-way (free)
#define HP0    168   // enc0 row: 128 h + 6 xhi + 6 xlo + 20 zero + 8 pad
#define YT     256   // UNPADDED y0-tile row (XOR-swizzled image, global_load_lds target)
#define W1LP   36    // enc1 LDS Wih k0..31 stride: 18 words, gcd(18,32)=2 -> 2-way (free)
#define WDP    68    // decoder LDS weight row stride (64 k + 4 pad): 34 words -> 2-way (free)
#define HORZ   360

__device__ __forceinline__ float bf2f_(unsigned short u){
  union { unsigned int i; float f; } v; v.i = ((unsigned int)u) << 16; return v.f;
}
__device__ __forceinline__ unsigned short f2bf(float f){
  union { float f; unsigned int i; } v; v.f = f;
  unsigned int r = v.i + 0x7fffu + ((v.i >> 16) & 1u);
  return (unsigned short)(r >> 16);
}
__device__ __forceinline__ float rcp_(float x){ return __builtin_amdgcn_rcpf(x); }
__device__ __forceinline__ float sigm(float x){ return rcp_(1.f + __expf(-x)); }
__device__ __forceinline__ float tanh_(float x){
  float a = fabsf(x);
  float e = __expf(-2.f * a);
  float t = (1.f - e) * rcp_(1.f + e);
  return x >= 0.f ? t : -t;
}
__device__ __forceinline__ bf16x8 cvt8(const float* p){
  bf16x8 r;
  #pragma unroll
  for (int i = 0; i < 8; ++i) r[i] = (short)f2bf(p[i]);
  return r;
}
// async global->LDS, 16B/lane; LDS dest = wave-uniform base + lane*16
__device__ __forceinline__ void gl_lds16(const unsigned short* g, unsigned short* l){
  __builtin_amdgcn_global_load_lds(
      (const __attribute__((address_space(1))) void*)(g),
      (__attribute__((address_space(3))) void*)(l), 16, 0, 0);
}

// ---------------------------------------------------------------------------
// Encoder layer 0 (bidirectional): 64 WGs x 256 thr (4 waves, 1/SIMD).
// Per wave: 128 N-cols, ALL weights in registers (40 frags). Single barrier,
// h ping-pong, K=160 MFMA folds x (hi/lo bf16 split).
// ---------------------------------------------------------------------------
__global__ __launch_bounds__(256, 1)
void enc_layer0_kernel(const float* __restrict__ x,
                       const float* __restrict__ WihF, const float* __restrict__ WhhF,
                       const float* __restrict__ bihF, const float* __restrict__ bhhF,
                       const float* __restrict__ WihB, const float* __restrict__ WhhB,
                       const float* __restrict__ bihB, const float* __restrict__ bhhB,
                       unsigned short* __restrict__ y0,
                       float* __restrict__ ench, float* __restrict__ encc)
{
  __shared__ __align__(16) unsigned short h_buf[2][BT * HP0];
  const int tid  = threadIdx.x;
  const int lane = tid & 63;
  const int w    = tid >> 6;      // 0..3
  const int l15  = lane & 15;
  const int q    = lane >> 4;
  const int dir  = blockIdx.x >> 5;
  const int bbase = (blockIdx.x & 31) * BT;

  const float* Wih = dir ? WihB : WihF;
  const float* Whh = dir ? WhhB : WhhF;
  const float* bih = dir ? bihB : bihF;
  const float* bhh = dir ? bhhB : bhhF;

  bf16x8 bw[4][2][5];       // [gate][u][kt]: Whh kt0..3 + x-fold kt4 (160 regs)
  float  bias[4][2];
  #pragma unroll
  for (int g = 0; g < 4; ++g)
    #pragma unroll
    for (int u = 0; u < 2; ++u) {
      const int n = g * 128 + w * 32 + u * 16 + l15;
      #pragma unroll
      for (int kt = 0; kt < 4; ++kt)
        bw[g][u][kt] = cvt8(Whh + n * HD + kt * 32 + q * 8);
      bf16x8 f;
      #pragma unroll
      for (int j = 0; j < 8; ++j) {
        const int kk = q * 8 + j;                 // col 128+kk
        float wv = 0.f;
        if (kk < 6)       wv = Wih[n * 6 + kk];        // x-hi cols
        else if (kk < 12) wv = Wih[n * 6 + (kk - 6)];  // x-lo cols
        f[j] = (short)f2bf(wv);
      }
      bw[g][u][4] = f;
      bias[g][u] = bih[n] + bhh[n];
    }

  int t = dir ? (T_SEQ - 1) : 0;
  const int dt = dir ? -1 : 1;
  const int xr_ = tid / 6, xk_ = tid % 6;       // valid for tid<96

  float cst[2][4] = {{0.f,0.f,0.f,0.f},{0.f,0.f,0.f,0.f}};
  for (int i = tid; i < 2 * BT * HP0; i += 256) (&h_buf[0][0])[i] = 0;
  __syncthreads();  // zeros visible before x-col writes
  float xv_cur = 0.f;
  if (tid < 96) {   // x(t0) -> buf0 ; preload x(t1)
    const float v0 = x[((size_t)(bbase + xr_) * T_SEQ + t) * 6 + xk_];
    const unsigned short hi = f2bf(v0);
    h_buf[0][xr_ * HP0 + 128 + xk_] = hi;
    h_buf[0][xr_ * HP0 + 134 + xk_] = f2bf(v0 - bf2f_(hi));
    xv_cur = x[((size_t)(bbase + xr_) * T_SEQ + t + dt) * 6 + xk_];
  }
  __syncthreads();

  for (int s = 0; s < T_SEQ; ++s, t += dt) {
    const int cur = s & 1, nxt = cur ^ 1;

    // y0 store for h(s-1); store-ack drains during this step's compute.
    if (s > 0) {
      const int b = tid >> 4, c8 = tid & 15;
      const bf16x8 hv = *reinterpret_cast<const bf16x8*>(&h_buf[cur][b * HP0 + c8 * 8]);
      *reinterpret_cast<bf16x8*>(y0 + ((size_t)(bbase + b) * T_SEQ + (t - dt)) * 256 + dir * HD + c8 * 8) = hv;
    }
    // prefetch x(t+2dt), consumed next step (full-step slack)
    float xv_next = 0.f;
    if (tid < 96 && s + 2 < T_SEQ)
      xv_next = x[((size_t)(bbase + xr_) * T_SEQ + (t + 2 * dt)) * 6 + xk_];

    f32x4 acc[4][2];
    #pragma unroll
    for (int g = 0; g < 4; ++g)
      #pragma unroll
      for (int u = 0; u < 2; ++u) {
        const float b = bias[g][u];
        acc[g][u][0] = b; acc[g][u][1] = b; acc[g][u][2] = b; acc[g][u][3] = b;
      }
    #pragma unroll
    for (int kt = 0; kt < 5; ++kt) {
      const bf16x8 af = *reinterpret_cast<const bf16x8*>(&h_buf[cur][l15 * HP0 + kt * 32 + q * 8]);
      #pragma unroll
      for (int g = 0; g < 4; ++g)
        #pragma unroll
        for (int u = 0; u < 2; ++u)
          acc[g][u] = MFMA16(af, bw[g][u][kt], acc[g][u]);
    }

    #pragma unroll
    for (int u = 0; u < 2; ++u)
      #pragma unroll
      for (int r = 0; r < 4; ++r) {
        const float i_ = acc[0][u][r], f_ = acc[1][u][r], g_ = acc[2][u][r], o_ = acc[3][u][r];
        const float c_ = sigm(f_) * cst[u][r] + sigm(i_) * tanh_(g_);
        cst[u][r] = c_;
        const float h_ = sigm(o_) * tanh_(c_);
        h_buf[nxt][(q * 4 + r) * HP0 + w * 32 + u * 16 + l15] = f2bf(h_);
        if (s == T_SEQ - 1) {
          const int b   = bbase + q * 4 + r;
          const int cix = w * 32 + u * 16 + l15;
          ench[(dir * NB + b) * HD + cix] = h_;
          encc[(dir * NB + b) * HD + cix] = c_;
        }
      }
    if (tid < 96 && s + 1 < T_SEQ) {   // x(s+1) -> buf[nxt]
      const unsigned short hi = f2bf(xv_cur);
      h_buf[nxt][xr_ * HP0 + 128 + xk_] = hi;
      h_buf[nxt][xr_ * HP0 + 134 + xk_] = f2bf(xv_cur - bf2f_(hi));
    }
    xv_cur = xv_next;
    __syncthreads();   // single barrier: nxt visible, cur free
  }
  // final y0 store for t(T-1)
  {
    const int cur = T_SEQ & 1;
    const int b = tid >> 4, c8 = tid & 15;
    const bf16x8 hv = *reinterpret_cast<const bf16x8*>(&h_buf[cur][b * HP0 + c8 * 8]);
    const int tl = dir ? 0 : (T_SEQ - 1);
    *reinterpret_cast<bf16x8*>(y0 + ((size_t)(bbase + b) * T_SEQ + tl) * 256 + dir * HD + c8 * 8) = hv;
  }
}

// ---------------------------------------------------------------------------
// Encoder layer 1: K=384 (y0 256 + h 128). 64 WGs x 256 thr (4 waves, 1/SIMD,
// 512-reg budget). Per wave 128 N-cols; 11 of 12 K-tiles in registers (352
// regs), only Wih k0..31 in LDS. Async global_load_lds y0 prefetch (2 issues
// per wave), h ping-pong, single barrier/step.
// ---------------------------------------------------------------------------
__global__ __launch_bounds__(256, 1)
void enc_layer1_kernel(const unsigned short* __restrict__ y0,
                       const float* __restrict__ WihF, const float* __restrict__ WhhF,
                       const float* __restrict__ bihF, const float* __restrict__ bhhF,
                       const float* __restrict__ WihB, const float* __restrict__ WhhB,
                       const float* __restrict__ bihB, const float* __restrict__ bhhB,
                       float* __restrict__ ench, float* __restrict__ encc)
{
  __shared__ __align__(16) unsigned short wlds[GD * W1LP];      // Wih k0..31
  __shared__ __align__(16) unsigned short ybuf[2][BT * YT];     // swizzled image
  __shared__ __align__(16) unsigned short h_buf[2][BT * HP];

  const int tid  = threadIdx.x;
  const int lane = tid & 63;
  const int w    = tid >> 6;      // 0..3
  const int l15  = lane & 15;
  const int q    = lane >> 4;
  const int dir  = blockIdx.x >> 5;
  const int bbase = (blockIdx.x & 31) * BT;

  const float* Wih = dir ? WihB : WihF;
  const float* Whh = dir ? WhhB : WhhF;
  const float* bih = dir ? bihB : bihF;
  const float* bhh = dir ? bhhB : bhhF;

  for (int i = tid; i < GD * 4; i += 256) {
    const int n = i >> 2, c8 = i & 3;
    *reinterpret_cast<bf16x8*>(&wlds[n * W1LP + c8 * 8]) = cvt8(Wih + n * 256 + c8 * 8);
  }

  bf16x8 bw[4][2][11];   // [g][u]: kt1..7 Wih k32..255 ; kt8..11 Whh (352 regs)
  float  bias[4][2];
  int    nofs[4][2];
  #pragma unroll
  for (int g = 0; g < 4; ++g)
    #pragma unroll
    for (int u = 0; u < 2; ++u) {
      const int n = g * 128 + w * 32 + u * 16 + l15;
      nofs[g][u] = n * W1LP;
      #pragma unroll
      for (int kt = 1; kt < 8; ++kt)
        bw[g][u][kt - 1] = cvt8(Wih + n * 256 + kt * 32 + q * 8);
      #pragma unroll
      for (int kt = 8; kt < 12; ++kt)
        bw[g][u][kt - 1] = cvt8(Whh + n * HD + (kt - 8) * 32 + q * 8);
      bias[g][u] = bih[n] + bhh[n];
    }

  // per-lane swizzled global source for global_load_lds; each wave covers
  // rows 4w..4w+3 in two issues (64 lanes x 16B = 2 rows of 512B).
  const int sb0  = 4 * w + (lane >> 5);         // rows 4w, 4w+1
  const int sb1  = sb0 + 2;                     // rows 4w+2, 4w+3
  const int cimg = lane & 31;
  const int sig0 = (cimg & 16) | ((cimg & 15) ^ (sb0 & 15));
  const int sig1 = (cimg & 16) | ((cimg & 15) ^ (sb1 & 15));
  const size_t grow0 = (size_t)(bbase + sb0) * T_SEQ * 256 + (size_t)sig0 * 8;
  const size_t grow1 = (size_t)(bbase + sb1) * T_SEQ * 256 + (size_t)sig1 * 8;
  unsigned short* ldA0 = &ybuf[0][(4 * w) * YT];
  unsigned short* ldA1 = &ybuf[0][(4 * w + 2) * YT];
  unsigned short* ldB0 = &ybuf[1][(4 * w) * YT];
  unsigned short* ldB1 = &ybuf[1][(4 * w + 2) * YT];

  int t = dir ? (T_SEQ - 1) : 0;
  const int dt = dir ? -1 : 1;

  float cst[2][4] = {{0.f,0.f,0.f,0.f},{0.f,0.f,0.f,0.f}};
  for (int i = tid; i < 2 * BT * HP; i += 256) (&h_buf[0][0])[i] = 0;
  gl_lds16(y0 + grow0 + (size_t)t * 256, ldA0);   // prologue tile t0
  gl_lds16(y0 + grow1 + (size_t)t * 256, ldA1);
  __syncthreads();                                 // drains vmcnt

  for (int s = 0; s < T_SEQ; ++s, t += dt) {
    const int cur = s & 1, nxt = cur ^ 1;

    if (s + 1 < T_SEQ) {   // async prefetch next tile; full step of slack
      gl_lds16(y0 + grow0 + (size_t)(t + dt) * 256, cur ? ldA0 : ldB0);
      gl_lds16(y0 + grow1 + (size_t)(t + dt) * 256, cur ? ldA1 : ldB1);
    }

    f32x4 acc[4][2];
    #pragma unroll
    for (int g = 0; g < 4; ++g)
      #pragma unroll
      for (int u = 0; u < 2; ++u) {
        const float b = bias[g][u];
        acc[g][u][0] = b; acc[g][u][1] = b; acc[g][u][2] = b; acc[g][u][3] = b;
      }
    {   // kt0: y0 chunk, B from LDS
      const int swz = q ^ l15;                    // c = q (0..3), c&16 = 0
      const bf16x8 af = *reinterpret_cast<const bf16x8*>(&ybuf[cur][l15 * YT + swz * 8]);
      #pragma unroll
      for (int g = 0; g < 4; ++g)
        #pragma unroll
        for (int u = 0; u < 2; ++u) {
          const bf16x8 bl = *reinterpret_cast<const bf16x8*>(&wlds[nofs[g][u] + q * 8]);
          acc[g][u] = MFMA16(af, bl, acc[g][u]);
        }
    }
    #pragma unroll
    for (int kt = 1; kt < 8; ++kt) {              // y0 chunks, B in regs
      const int c   = kt * 4 + q;
      const int swz = (c & 16) | ((c & 15) ^ l15);
      const bf16x8 af = *reinterpret_cast<const bf16x8*>(&ybuf[cur][l15 * YT + swz * 8]);
      #pragma unroll
      for (int g = 0; g < 4; ++g)
        #pragma unroll
        for (int u = 0; u < 2; ++u)
          acc[g][u] = MFMA16(af, bw[g][u][kt - 1], acc[g][u]);
    }
    #pragma unroll
    for (int kt = 8; kt < 12; ++kt) {             // h chunks, B in regs
      const bf16x8 af = *reinterpret_cast<const bf16x8*>(&h_buf[cur][l15 * HP + (kt - 8) * 32 + q * 8]);
      #pragma unroll
      for (int g = 0; g < 4; ++g)
        #pragma unroll
        for (int u = 0; u < 2; ++u)
          acc[g][u] = MFMA16(af, bw[g][u][kt - 1], acc[g][u]);
    }

    #pragma unroll
    for (int u = 0; u < 2; ++u)
      #pragma unroll
      for (int r = 0; r < 4; ++r) {
        const float i_ = acc[0][u][r], f_ = acc[1][u][r], g_ = acc[2][u][r], o_ = acc[3][u][r];
        const float c_ = sigm(f_) * cst[u][r] + sigm(i_) * tanh_(g_);
        cst[u][r] = c_;
        const float h_ = sigm(o_) * tanh_(c_);
        h_buf[nxt][(q * 4 + r) * HP + w * 32 + u * 16 + l15] = f2bf(h_);
        if (s == T_SEQ - 1) {
          const int b   = bbase + q * 4 + r;
          const int cix = w * 32 + u * 16 + l15;
          ench[(dir * NB + b) * HD + cix] = h_;
          encc[(dir * NB + b) * HD + cix] = c_;
        }
      }
    __syncthreads();   // single barrier: drains async load, flips buffers
  }
}

// ---------------------------------------------------------------------------
// Bridge: h_dec = h_enc @ brh_W.T + brh_b ; same for c with brc. Pure fp32.
// ---------------------------------------------------------------------------
__global__ void bridge_kernel(const float* __restrict__ ench0, const float* __restrict__ encc0,
                              const float* __restrict__ ench1, const float* __restrict__ encc1,
                              const float* __restrict__ brhW, const float* __restrict__ brhb,
                              const float* __restrict__ brcW, const float* __restrict__ brcb,
                              float* __restrict__ dech, float* __restrict__ decc)
{
  const int idx = blockIdx.x * 256 + threadIdx.x;   // 262144 total
  const int sel = idx >> 17;          // 0: h, 1: c
  const int l   = (idx >> 16) & 1;    // layer
  const int b   = (idx >> 7) & 511;
  const int j   = idx & 127;
  const float* W  = sel ? brcW : brhW;
  const float* bb = sel ? brcb : brhb;
  const float* s0 = sel ? (l ? encc1 : encc0) : (l ? ench1 : ench0);
  float a = bb[j];
  for (int k = 0; k < 128; ++k) a += W[j * 256 + k] * s0[b * 128 + k];
  for (int k = 0; k < 128; ++k) a += W[j * 256 + 128 + k] * s0[(512 + b) * 128 + k];
  float* dst = sel ? decc : dech;
  dst[(l * 512 + b) * 128 + j] = a;
}

// ---------------------------------------------------------------------------
// Decoder (R4 config — fastest measured): 512 thr, W0hh/W1ih k0..63 in LDS,
// rest in regs; 2 barriers/step; out-proj redundant on all waves + shfl.
// ---------------------------------------------------------------------------
__global__ __launch_bounds__(512, 2)
void decoder_kernel(const float* __restrict__ dech, const float* __restrict__ decc,
                    const float* __restrict__ W0ih, const float* __restrict__ W0hh,
                    const float* __restrict__ b0ih, const float* __restrict__ b0hh,
                    const float* __restrict__ W1ih, const float* __restrict__ W1hh,
                    const float* __restrict__ b1ih, const float* __restrict__ b1hh,
                    const float* __restrict__ outW, const float* __restrict__ outb,
                    const float* __restrict__ stok,
                    float* __restrict__ out)
{
  __shared__ __align__(16) unsigned short w0lds[GD * WDP];   // W0hh k0..63
  __shared__ __align__(16) unsigned short w1lds[GD * WDP];   // W1ih k0..63
  __shared__ __align__(16) unsigned short h0_buf[2][BT * HP];
  __shared__ __align__(16) unsigned short h1_buf[2][BT * HP];

  const int tid  = threadIdx.x;
  const int lane = tid & 63;
  const int w    = tid >> 6;      // 0..7
  const int l15  = lane & 15;
  const int q    = lane >> 4;
  const int bbase = blockIdx.x * BT;

  for (int i = tid; i < GD * 8; i += 512) {
    const int n = i >> 3, c8 = i & 7;
    *reinterpret_cast<bf16x8*>(&w0lds[n * WDP + c8 * 8]) = cvt8(W0hh + n * HD + c8 * 8);
    *reinterpret_cast<bf16x8*>(&w1lds[n * WDP + c8 * 8]) = cvt8(W1ih + n * HD + c8 * 8);
  }

  bf16x8 bw0[4][2];    // W0hh k64..127
  bf16x8 bw1[4][6];    // W1ih k64..127 (2) + W1hh k0..127 (4)
  float  xw0[4][3], bias0[4], bias1[4];
  int    nofs[4];
  #pragma unroll
  for (int g = 0; g < 4; ++g) {
    const int n = g * 128 + w * 16 + l15;
    nofs[g] = n * WDP;
    #pragma unroll
    for (int kt = 2; kt < 4; ++kt) {
      bw0[g][kt - 2] = cvt8(W0hh + n * HD + kt * 32 + q * 8);
      bw1[g][kt - 2] = cvt8(W1ih + n * HD + kt * 32 + q * 8);
    }
    #pragma unroll
    for (int kt = 4; kt < 8; ++kt)
      bw1[g][kt - 2] = cvt8(W1hh + n * HD + (kt - 4) * 32 + q * 8);
    #pragma unroll
    for (int k = 0; k < 3; ++k) xw0[g][k] = W0ih[n * 3 + k];
    bias0[g] = b0ih[n] + b0hh[n];
    bias1[g] = b1ih[n] + b1hh[n];
  }

  // out-projection fragments on ALL waves (redundant compute kills a barrier)
  bf16x8 owf[4];
  float outb_s = 0.f;
  {
    bf16x8 z;
    #pragma unroll
    for (int i = 0; i < 8; ++i) z[i] = 0;
    #pragma unroll
    for (int kt = 0; kt < 4; ++kt) owf[kt] = z;
    if (l15 < 3) {
      #pragma unroll
      for (int kt = 0; kt < 4; ++kt) owf[kt] = cvt8(outW + l15 * HD + kt * 32 + q * 8);
      outb_s = outb[l15];
    }
  }

  float c0[4], c1[4];
  #pragma unroll
  for (int r = 0; r < 4; ++r) {
    const int b   = bbase + q * 4 + r;
    const int cix = w * 16 + l15;
    c0[r] = decc[b * HD + cix];
    c1[r] = decc[(NB + b) * HD + cix];
  }
  for (int i = tid; i < BT * HD; i += 512) {
    const int b = i >> 7, cix = i & 127;
    h0_buf[0][b * HP + cix] = f2bf(dech[(bbase + b) * HD + cix]);
    h1_buf[0][b * HP + cix] = f2bf(dech[(NB + bbase + b) * HD + cix]);
  }
  float xr[4][3];
  {
    const float s0 = stok[0], s1 = stok[1], s2 = stok[2];
    #pragma unroll
    for (int r = 0; r < 4; ++r) { xr[r][0] = s0; xr[r][1] = s1; xr[r][2] = s2; }
  }
  __syncthreads();

  for (int s = 0; s < HORZ; ++s) {
    const int cur = s & 1, nxt = cur ^ 1;

    // ---- cell 0 ----
    f32x4 acc[4];
    #pragma unroll
    for (int g = 0; g < 4; ++g)
      #pragma unroll
      for (int r = 0; r < 4; ++r)
        acc[g][r] = bias0[g] + xw0[g][0] * xr[r][0] + xw0[g][1] * xr[r][1] + xw0[g][2] * xr[r][2];
    #pragma unroll
    for (int kt = 0; kt < 2; ++kt) {
      const bf16x8 af = *reinterpret_cast<const bf16x8*>(&h0_buf[cur][l15 * HP + kt * 32 + q * 8]);
      #pragma unroll
      for (int g = 0; g < 4; ++g) {
        const bf16x8 bl = *reinterpret_cast<const bf16x8*>(&w0lds[nofs[g] + kt * 32 + q * 8]);
        acc[g] = MFMA16(af, bl, acc[g]);
      }
    }
    #pragma unroll
    for (int kt = 2; kt < 4; ++kt) {
      const bf16x8 af = *reinterpret_cast<const bf16x8*>(&h0_buf[cur][l15 * HP + kt * 32 + q * 8]);
      #pragma unroll
      for (int g = 0; g < 4; ++g) acc[g] = MFMA16(af, bw0[g][kt - 2], acc[g]);
    }
    #pragma unroll
    for (int r = 0; r < 4; ++r) {
      const float i_ = acc[0][r], f_ = acc[1][r], g_ = acc[2][r], o_ = acc[3][r];
      const float c_ = sigm(f_) * c0[r] + sigm(i_) * tanh_(g_);
      c0[r] = c_;
      const float h_ = sigm(o_) * tanh_(c_);
      h0_buf[nxt][(q * 4 + r) * HP + w * 16 + l15] = f2bf(h_);
    }
    __syncthreads();   // barrier A: h0 new visible

    // ---- cell 1 ----
    #pragma unroll
    for (int g = 0; g < 4; ++g) {
      acc[g][0] = bias1[g]; acc[g][1] = bias1[g];
      acc[g][2] = bias1[g]; acc[g][3] = bias1[g];
    }
    #pragma unroll
    for (int kt = 0; kt < 2; ++kt) {
      const bf16x8 af = *reinterpret_cast<const bf16x8*>(&h0_buf[nxt][l15 * HP + kt * 32 + q * 8]);
      #pragma unroll
      for (int g = 0; g < 4; ++g) {
        const bf16x8 bl = *reinterpret_cast<const bf16x8*>(&w1lds[nofs[g] + kt * 32 + q * 8]);
        acc[g] = MFMA16(af, bl, acc[g]);
      }
    }
    #pragma unroll
    for (int kt = 2; kt < 4; ++kt) {
      const bf16x8 af = *reinterpret_cast<const bf16x8*>(&h0_buf[nxt][l15 * HP + kt * 32 + q * 8]);
      #pragma unroll
      for (int g = 0; g < 4; ++g) acc[g] = MFMA16(af, bw1[g][kt - 2], acc[g]);
    }
    #pragma unroll
    for (int kt = 4; kt < 8; ++kt) {
      const bf16x8 af = *reinterpret_cast<const bf16x8*>(&h1_buf[cur][l15 * HP + (kt - 4) * 32 + q * 8]);
      #pragma unroll
      for (int g = 0; g < 4; ++g) acc[g] = MFMA16(af, bw1[g][kt - 2], acc[g]);
    }
    #pragma unroll
    for (int r = 0; r < 4; ++r) {
      const float i_ = acc[0][r], f_ = acc[1][r], g_ = acc[2][r], o_ = acc[3][r];
      const float c_ = sigm(f_) * c1[r] + sigm(i_) * tanh_(g_);
      c1[r] = c_;
      const float h_ = sigm(o_) * tanh_(c_);
      h1_buf[nxt][(q * 4 + r) * HP + w * 16 + l15] = f2bf(h_);
    }
    __syncthreads();   // barrier B: h1 new visible

    // ---- out projection (all waves, redundant) + shfl feedback ----
    f32x4 p = {0.f, 0.f, 0.f, 0.f};
    #pragma unroll
    for (int kt = 0; kt < 4; ++kt) {
      const bf16x8 af = *reinterpret_cast<const bf16x8*>(&h1_buf[nxt][l15 * HP + kt * 32 + q * 8]);
      p = MFMA16(af, owf[kt], p);
    }
    float pb[4];
    #pragma unroll
    for (int r = 0; r < 4; ++r) pb[r] = p[r] + outb_s;
    if (w == 0 && l15 < 3) {
      #pragma unroll
      for (int r = 0; r < 4; ++r)
        out[((size_t)(bbase + q * 4 + r) * HORZ + s) * 3 + l15] = pb[r];
    }
    #pragma unroll
    for (int r = 0; r < 4; ++r)
      #pragma unroll
      for (int c = 0; c < 3; ++c)
        xr[r][c] = __shfl(pb[r], (q << 4) + c, 64);
    // no barrier: next step writes touch opposite buffers only
  }
}

// ---------------------------------------------------------------------------
extern "C" void kernel_launch(void* const* d_in, const int* in_sizes, int n_in,
                              void* d_out, int out_size, void* d_ws, size_t ws_size,
                              hipStream_t stream)
{
  (void)in_sizes; (void)n_in; (void)out_size; (void)ws_size;
  const float* x      = (const float*)d_in[0];
  const float* e0fWih = (const float*)d_in[1];
  const float* e0fWhh = (const float*)d_in[2];
  const float* e0fbih = (const float*)d_in[3];
  const float* e0fbhh = (const float*)d_in[4];
  const float* e0bWih = (const float*)d_in[5];
  const float* e0bWhh = (const float*)d_in[6];
  const float* e0bbih = (const float*)d_in[7];
  const float* e0bbhh = (const float*)d_in[8];
  const float* e1fWih = (const float*)d_in[9];
  const float* e1fWhh = (const float*)d_in[10];
  const float* e1fbih = (const float*)d_in[11];
  const float* e1fbhh = (const float*)d_in[12];
  const float* e1bWih = (const float*)d_in[13];
  const float* e1bWhh = (const float*)d_in[14];
  const float* e1bbih = (const float*)d_in[15];
  const float* e1bbhh = (const float*)d_in[16];
  const float* brhW   = (const float*)d_in[17];
  const float* brhb   = (const float*)d_in[18];
  const float* brcW   = (const float*)d_in[19];
  const float* brcb   = (const float*)d_in[20];
  const float* d0Wih  = (const float*)d_in[21];
  const float* d0Whh  = (const float*)d_in[22];
  const float* d0bih  = (const float*)d_in[23];
  const float* d0bhh  = (const float*)d_in[24];
  const float* d1Wih  = (const float*)d_in[25];
  const float* d1Whh  = (const float*)d_in[26];
  const float* d1bih  = (const float*)d_in[27];
  const float* d1bhh  = (const float*)d_in[28];
  const float* outW   = (const float*)d_in[29];
  const float* outb   = (const float*)d_in[30];
  const float* stok   = (const float*)d_in[31];

  char* ws = (char*)d_ws;
  unsigned short* y0 = (unsigned short*)ws;                        // internal bf16
  size_t off = (size_t)NB * T_SEQ * 256 * sizeof(unsigned short);  // 188.7 MB
  const size_t blk = (size_t)2 * NB * HD * sizeof(float);          // 512 KB each
  float* ench0 = (float*)(ws + off); off += blk;
  float* encc0 = (float*)(ws + off); off += blk;
  float* ench1 = (float*)(ws + off); off += blk;
  float* encc1 = (float*)(ws + off); off += blk;
  float* dech  = (float*)(ws + off); off += blk;
  float* decc  = (float*)(ws + off); off += blk;

  enc_layer0_kernel<<<dim3(64), dim3(256), 0, stream>>>(
      x, e0fWih, e0fWhh, e0fbih, e0fbhh, e0bWih, e0bWhh, e0bbih, e0bbhh,
      y0, ench0, encc0);
  enc_layer1_kernel<<<dim3(64), dim3(256), 0, stream>>>(
      y0, e1fWih, e1fWhh, e1fbih, e1fbhh, e1bWih, e1bWhh, e1bbih, e1bbhh,
      ench1, encc1);
  bridge_kernel<<<dim3(1024), dim3(256), 0, stream>>>(
      ench0, encc0, ench1, encc1, brhW, brhb, brcW, brcb, dech, decc);
  decoder_kernel<<<dim3(32), dim3(512), 0, stream>>>(
      dech, decc, d0Wih, d0Whh, d0bih, d0bhh, d1Wih, d1Whh, d1bih, d1bhh,
      outW, outb, stok, (float*)d_out);
}

// Round 7
// 3546.559 us; speedup vs baseline: 1.0149x; 1.0149x over previous
//
#include <hip/hip_runtime.h>

typedef __attribute__((ext_vector_type(8))) short bf16x8;
typedef __attribute__((ext_vector_type(4))) float f32x4;

#define MFMA16(a,b,c) __builtin_amdgcn_mfma_f32_16x16x32_bf16((a),(b),(c),0,0,0)

#define T_SEQ  720
#define NB     512
#define HD     128
#define GD     512
#define BT     16
#define HP     136   // h row stride: 68 words % 32 banks = 4 -> 2-way (free)
#define HP0    168   // enc0 row: 128 h + 6 xhi + 6 xlo + 20 zero + 8 pad
#define YT     256   // UNPADDED y0-tile row (XOR-swizzled image, global_load_lds target)
#define WLP    68    // LDS weight row stride (64 k + 4 pad): 34 words -> 2-way (free)
#define HORZ   360

__device__ __forceinline__ float bf2f_(unsigned short u){
  union { unsigned int i; float f; } v; v.i = ((unsigned int)u) << 16; return v.f;
}
__device__ __forceinline__ unsigned short f2bf(float f){
  union { float f; unsigned int i; } v; v.f = f;
  unsigned int r = v.i + 0x7fffu + ((v.i >> 16) & 1u);
  return (unsigned short)(r >> 16);
}
__device__ __forceinline__ float rcp_(float x){ return __builtin_amdgcn_rcpf(x); }
__device__ __forceinline__ float sigm(float x){ return rcp_(1.f + __expf(-x)); }
__device__ __forceinline__ float tanh_(float x){
  float a = fabsf(x);
  float e = __expf(-2.f * a);
  float t = (1.f - e) * rcp_(1.f + e);
  return x >= 0.f ? t : -t;
}
__device__ __forceinline__ bf16x8 cvt8(const float* p){
  bf16x8 r;
  #pragma unroll
  for (int i = 0; i < 8; ++i) r[i] = (short)f2bf(p[i]);
  return r;
}
// async global->LDS, 16B/lane; LDS dest = wave-uniform base + lane*16
__device__ __forceinline__ void gl_lds16(const unsigned short* g, unsigned short* l){
  __builtin_amdgcn_global_load_lds(
      (const __attribute__((address_space(1))) void*)(g),
      (__attribute__((address_space(3))) void*)(l), 16, 0, 0);
}

// ---------------------------------------------------------------------------
// Encoder layer 0 (bidirectional): 64 WGs x 512 thr. Single barrier/step,
// h ping-pong, K=160 MFMA folds x (hi/lo bf16 split). (R4 config, best.)
// ---------------------------------------------------------------------------
__global__ __launch_bounds__(512, 2)
void enc_layer0_kernel(const float* __restrict__ x,
                       const float* __restrict__ WihF, const float* __restrict__ WhhF,
                       const float* __restrict__ bihF, const float* __restrict__ bhhF,
                       const float* __restrict__ WihB, const float* __restrict__ WhhB,
                       const float* __restrict__ bihB, const float* __restrict__ bhhB,
                       unsigned short* __restrict__ y0,
                       float* __restrict__ ench, float* __restrict__ encc)
{
  __shared__ __align__(16) unsigned short h_buf[2][BT * HP0];
  const int tid  = threadIdx.x;
  const int lane = tid & 63;
  const int w    = tid >> 6;      // 0..7
  const int l15  = lane & 15;
  const int q    = lane >> 4;
  const int dir  = blockIdx.x >> 5;
  const int bbase = (blockIdx.x & 31) * BT;

  const float* Wih = dir ? WihB : WihF;
  const float* Whh = dir ? WhhB : WhhF;
  const float* bih = dir ? bihB : bihF;
  const float* bhh = dir ? bhhB : bhhF;

  bf16x8 bw[4][5];          // per gate: Whh kt0..3 + x-fold kt4
  f32x4  bias_vec[4];
  #pragma unroll
  for (int g = 0; g < 4; ++g) {
    const int n = g * 128 + w * 16 + l15;
    #pragma unroll
    for (int kt = 0; kt < 4; ++kt)
      bw[g][kt] = cvt8(Whh + n * HD + kt * 32 + q * 8);
    bf16x8 f;
    #pragma unroll
    for (int j = 0; j < 8; ++j) {
      const int kk = q * 8 + j;                 // col 128+kk
      float wv = 0.f;
      if (kk < 6)       wv = Wih[n * 6 + kk];        // x-hi cols
      else if (kk < 12) wv = Wih[n * 6 + (kk - 6)];  // x-lo cols
      f[j] = (short)f2bf(wv);
    }
    bw[g][4] = f;
    const float b = bih[n] + bhh[n];
    bias_vec[g][0] = b; bias_vec[g][1] = b; bias_vec[g][2] = b; bias_vec[g][3] = b;
  }

  int t = dir ? (T_SEQ - 1) : 0;
  const int dt = dir ? -1 : 1;
  const int xr_ = tid / 6, xk_ = tid % 6;       // valid for tid<96

  float cst[4] = {0.f, 0.f, 0.f, 0.f};
  for (int i = tid; i < 2 * BT * HP0; i += 512) (&h_buf[0][0])[i] = 0;
  __syncthreads();  // zeros visible before x-col writes
  float xv_cur = 0.f;
  if (tid < 96) {   // x(t0) -> buf0 ; preload x(t1)
    const float v0 = x[((size_t)(bbase + xr_) * T_SEQ + t) * 6 + xk_];
    const unsigned short hi = f2bf(v0);
    h_buf[0][xr_ * HP0 + 128 + xk_] = hi;
    h_buf[0][xr_ * HP0 + 134 + xk_] = f2bf(v0 - bf2f_(hi));
    xv_cur = x[((size_t)(bbase + xr_) * T_SEQ + t + dt) * 6 + xk_];
  }
  __syncthreads();

  for (int s = 0; s < T_SEQ; ++s, t += dt) {
    const int cur = s & 1, nxt = cur ^ 1;

    if (s > 0 && tid < 256) {   // y0 store for h(s-1); drains during compute
      const int b = tid >> 4, c8 = tid & 15;
      const bf16x8 hv = *reinterpret_cast<const bf16x8*>(&h_buf[cur][b * HP0 + c8 * 8]);
      *reinterpret_cast<bf16x8*>(y0 + ((size_t)(bbase + b) * T_SEQ + (t - dt)) * 256 + dir * HD + c8 * 8) = hv;
    }
    float xv_next = 0.f;
    if (tid < 96 && s + 2 < T_SEQ)
      xv_next = x[((size_t)(bbase + xr_) * T_SEQ + (t + 2 * dt)) * 6 + xk_];

    f32x4 acc[4];
    #pragma unroll
    for (int kt = 0; kt < 5; ++kt) {
      const bf16x8 af = *reinterpret_cast<const bf16x8*>(&h_buf[cur][l15 * HP0 + kt * 32 + q * 8]);
      #pragma unroll
      for (int g = 0; g < 4; ++g)
        acc[g] = MFMA16(af, bw[g][kt], kt == 0 ? bias_vec[g] : acc[g]);
    }

    #pragma unroll
    for (int r = 0; r < 4; ++r) {
      const float i_ = acc[0][r], f_ = acc[1][r], g_ = acc[2][r], o_ = acc[3][r];
      const float c_ = sigm(f_) * cst[r] + sigm(i_) * tanh_(g_);
      cst[r] = c_;
      const float h_ = sigm(o_) * tanh_(c_);
      h_buf[nxt][(q * 4 + r) * HP0 + w * 16 + l15] = f2bf(h_);
      if (s == T_SEQ - 1) {
        const int b   = bbase + q * 4 + r;
        const int cix = w * 16 + l15;
        ench[(dir * NB + b) * HD + cix] = h_;
        encc[(dir * NB + b) * HD + cix] = c_;
      }
    }
    if (tid < 96 && s + 1 < T_SEQ) {   // x(s+1) -> buf[nxt]
      const unsigned short hi = f2bf(xv_cur);
      h_buf[nxt][xr_ * HP0 + 128 + xk_] = hi;
      h_buf[nxt][xr_ * HP0 + 134 + xk_] = f2bf(xv_cur - bf2f_(hi));
    }
    xv_cur = xv_next;
    __syncthreads();   // single barrier: nxt visible, cur free
  }
  if (tid < 256) {   // final y0 store
    const int cur = T_SEQ & 1;
    const int b = tid >> 4, c8 = tid & 15;
    const bf16x8 hv = *reinterpret_cast<const bf16x8*>(&h_buf[cur][b * HP0 + c8 * 8]);
    const int tl = dir ? 0 : (T_SEQ - 1);
    *reinterpret_cast<bf16x8*>(y0 + ((size_t)(bbase + b) * T_SEQ + tl) * 256 + dir * HD + c8 * 8) = hv;
  }
}

// ---------------------------------------------------------------------------
// Encoder layer 1 (PIPELINED): K=384. h-dep part (Whh, 4 kt) chains onto a
// y0-partial precomputed one step ahead; y0 tiles triple-buffered with
// global_load_lds issued 2 steps ahead. 512 thr, Wih k0..63 in LDS,
// kt2..11 in regs/AGPRs (R4 balance).
// ---------------------------------------------------------------------------
#define ENC1_YPART(ACC, YB)                                                    \
  {                                                                            \
    _Pragma("unroll")                                                          \
    for (int g = 0; g < 4; ++g) {                                              \
      (ACC)[g][0] = bias[g]; (ACC)[g][1] = bias[g];                            \
      (ACC)[g][2] = bias[g]; (ACC)[g][3] = bias[g];                            \
    }                                                                          \
    _Pragma("unroll")                                                          \
    for (int kt = 0; kt < 2; ++kt) {                                           \
      const int swz_ = ((kt * 4 + q) & 15) ^ l15;                              \
      const bf16x8 af = *reinterpret_cast<const bf16x8*>(&(YB)[l15 * YT + swz_ * 8]); \
      _Pragma("unroll")                                                        \
      for (int g = 0; g < 4; ++g) {                                            \
        const bf16x8 bl = *reinterpret_cast<const bf16x8*>(&wlds[nofs[g] + kt * 32 + q * 8]); \
        (ACC)[g] = MFMA16(af, bl, (ACC)[g]);                                   \
      }                                                                        \
    }                                                                          \
    _Pragma("unroll")                                                          \
    for (int kt = 2; kt < 8; ++kt) {                                           \
      const int c_ = kt * 4 + q;                                               \
      const int swz_ = (c_ & 16) | ((c_ & 15) ^ l15);                          \
      const bf16x8 af = *reinterpret_cast<const bf16x8*>(&(YB)[l15 * YT + swz_ * 8]); \
      _Pragma("unroll")                                                        \
      for (int g = 0; g < 4; ++g) (ACC)[g] = MFMA16(af, bw[g][kt - 2], (ACC)[g]); \
    }                                                                          \
  }

#define ENC1_BODY(S, CUR, NXT, ACCC, ACCN)                                     \
  {                                                                            \
    if ((S) + 2 < T_SEQ)                                                       \
      gl_lds16(y0 + grow + (size_t)(t + 2 * dt) * 256, b2 + w * 512);          \
    _Pragma("unroll")                                                          \
    for (int kt = 8; kt < 12; ++kt) {                                          \
      const bf16x8 af = *reinterpret_cast<const bf16x8*>(&h_buf[CUR][l15 * HP + (kt - 8) * 32 + q * 8]); \
      _Pragma("unroll")                                                        \
      for (int g = 0; g < 4; ++g) (ACCC)[g] = MFMA16(af, bw[g][kt - 2], (ACCC)[g]); \
    }                                                                          \
    if ((S) + 1 < T_SEQ) ENC1_YPART(ACCN, b1)                                  \
    _Pragma("unroll")                                                          \
    for (int r = 0; r < 4; ++r) {                                              \
      const float i_ = (ACCC)[0][r], f_ = (ACCC)[1][r];                        \
      const float g_ = (ACCC)[2][r], o_ = (ACCC)[3][r];                        \
      const float cc_ = sigm(f_) * cst[r] + sigm(i_) * tanh_(g_);              \
      cst[r] = cc_;                                                            \
      const float h_ = sigm(o_) * tanh_(cc_);                                  \
      h_buf[NXT][(q * 4 + r) * HP + w * 16 + l15] = f2bf(h_);                  \
      if ((S) == T_SEQ - 1) {                                                  \
        const int b_ = bbase + q * 4 + r;                                      \
        const int cix = w * 16 + l15;                                          \
        ench[(dir * NB + b_) * HD + cix] = h_;                                 \
        encc[(dir * NB + b_) * HD + cix] = cc_;                                \
      }                                                                        \
    }                                                                          \
    { unsigned short* tmp_ = b0; b0 = b1; b1 = b2; b2 = tmp_; }                \
    t += dt;                                                                   \
    __syncthreads();                                                           \
  }

__global__ __launch_bounds__(512, 2)
void enc_layer1_kernel(const unsigned short* __restrict__ y0,
                       const float* __restrict__ WihF, const float* __restrict__ WhhF,
                       const float* __restrict__ bihF, const float* __restrict__ bhhF,
                       const float* __restrict__ WihB, const float* __restrict__ WhhB,
                       const float* __restrict__ bihB, const float* __restrict__ bhhB,
                       float* __restrict__ ench, float* __restrict__ encc)
{
  __shared__ __align__(16) unsigned short wlds[GD * WLP];       // Wih k0..63
  __shared__ __align__(16) unsigned short ybuf[3][BT * YT];     // triple buffer
  __shared__ __align__(16) unsigned short h_buf[2][BT * HP];

  const int tid  = threadIdx.x;
  const int lane = tid & 63;
  const int w    = tid >> 6;      // 0..7
  const int l15  = lane & 15;
  const int q    = lane >> 4;
  const int dir  = blockIdx.x >> 5;
  const int bbase = (blockIdx.x & 31) * BT;

  const float* Wih = dir ? WihB : WihF;
  const float* Whh = dir ? WhhB : WhhF;
  const float* bih = dir ? bihB : bihF;
  const float* bhh = dir ? bhhB : bhhF;

  for (int i = tid; i < GD * 8; i += 512) {
    const int n = i >> 3, c8 = i & 7;
    *reinterpret_cast<bf16x8*>(&wlds[n * WLP + c8 * 8]) = cvt8(Wih + n * 256 + c8 * 8);
  }

  bf16x8 bw[4][10];   // kt2..7: Wih k64..255 ; kt8..11: Whh k0..127
  float  bias[4];
  int    nofs[4];
  #pragma unroll
  for (int g = 0; g < 4; ++g) {
    const int n = g * 128 + w * 16 + l15;
    nofs[g] = n * WLP;
    #pragma unroll
    for (int kt = 2; kt < 8; ++kt)  bw[g][kt - 2] = cvt8(Wih + n * 256 + kt * 32 + q * 8);
    #pragma unroll
    for (int kt = 8; kt < 12; ++kt) bw[g][kt - 2] = cvt8(Whh + n * HD + (kt - 8) * 32 + q * 8);
    bias[g] = bih[n] + bhh[n];
  }

  // per-lane swizzled global source for global_load_lds
  const int sb   = 2 * w + (lane >> 5);         // batch row 0..15
  const int cimg = lane & 31;
  const int sig  = (cimg & 16) | ((cimg & 15) ^ (sb & 15));
  const size_t grow = (size_t)(bbase + sb) * T_SEQ * 256 + (size_t)sig * 8;
  unsigned short* b0 = &ybuf[0][0];
  unsigned short* b1 = &ybuf[1][0];
  unsigned short* b2 = &ybuf[2][0];

  int t = dir ? (T_SEQ - 1) : 0;
  const int dt = dir ? -1 : 1;

  float cst[4] = {0.f, 0.f, 0.f, 0.f};
  for (int i = tid; i < 2 * BT * HP; i += 512) (&h_buf[0][0])[i] = 0;
  gl_lds16(y0 + grow + (size_t)t * 256,        b0 + w * 512);   // tile 0
  gl_lds16(y0 + grow + (size_t)(t + dt) * 256, b1 + w * 512);   // tile 1
  __syncthreads();                                               // drains vmcnt

  f32x4 accP[4], accQ[4];
  ENC1_YPART(accP, b0)   // y0-partial for step 0

  for (int m = 0; m < T_SEQ / 2; ++m) {
    const int s0 = 2 * m;
    ENC1_BODY(s0,     0, 1, accP, accQ)
    ENC1_BODY(s0 + 1, 1, 0, accQ, accP)
  }
}

// ---------------------------------------------------------------------------
// Bridge: h_dec = h_enc @ brh_W.T + brh_b ; same for c with brc. Pure fp32.
// ---------------------------------------------------------------------------
__global__ void bridge_kernel(const float* __restrict__ ench0, const float* __restrict__ encc0,
                              const float* __restrict__ ench1, const float* __restrict__ encc1,
                              const float* __restrict__ brhW, const float* __restrict__ brhb,
                              const float* __restrict__ brcW, const float* __restrict__ brcb,
                              float* __restrict__ dech, float* __restrict__ decc)
{
  const int idx = blockIdx.x * 256 + threadIdx.x;   // 262144 total
  const int sel = idx >> 17;          // 0: h, 1: c
  const int l   = (idx >> 16) & 1;    // layer
  const int b   = (idx >> 7) & 511;
  const int j   = idx & 127;
  const float* W  = sel ? brcW : brhW;
  const float* bb = sel ? brcb : brhb;
  const float* s0 = sel ? (l ? encc1 : encc0) : (l ? ench1 : ench0);
  float a = bb[j];
  for (int k = 0; k < 128; ++k) a += W[j * 256 + k] * s0[b * 128 + k];
  for (int k = 0; k < 128; ++k) a += W[j * 256 + 128 + k] * s0[(512 + b) * 128 + k];
  float* dst = sel ? decc : dech;
  dst[(l * 512 + b) * 128 + j] = a;
}

// ---------------------------------------------------------------------------
// Decoder (PIPELINED): cell0's W0hh x h0 and cell1's W1hh x h1 parts are
// precomputed in the previous step's shadow; cell0 has NO MFMA on the
// critical path. 512 thr, W0hh/W1ih k0..63 in LDS, rest regs; 2 barriers.
// ---------------------------------------------------------------------------
#define DEC_BODY(S, CUR, NXT, ACC0C, ACC0N)                                    \
  {                                                                            \
    /* cell1 h1-part: accB = bias1 + W1hh x h1(S-1) (h1_buf[CUR]) */           \
    f32x4 accB[4];                                                             \
    _Pragma("unroll")                                                          \
    for (int g = 0; g < 4; ++g) {                                              \
      accB[g][0] = bias1[g]; accB[g][1] = bias1[g];                            \
      accB[g][2] = bias1[g]; accB[g][3] = bias1[g];                            \
    }                                                                          \
    _Pragma("unroll")                                                          \
    for (int kt = 4; kt < 8; ++kt) {                                           \
      const bf16x8 af = *reinterpret_cast<const bf16x8*>(&h1_buf[CUR][l15 * HP + (kt - 4) * 32 + q * 8]); \
      _Pragma("unroll")                                                        \
      for (int g = 0; g < 4; ++g) accB[g] = MFMA16(af, bw1[g][kt - 2], accB[g]); \
    }                                                                          \
    /* cell0 activation: gates = ACC0C + W0ih*xin (no MFMA) */                 \
    _Pragma("unroll")                                                          \
    for (int r = 0; r < 4; ++r) {                                              \
      float gv[4];                                                             \
      _Pragma("unroll")                                                        \
      for (int g = 0; g < 4; ++g)                                              \
        gv[g] = (ACC0C)[g][r] + xw0[g][0] * xr[r][0] + xw0[g][1] * xr[r][1] + xw0[g][2] * xr[r][2]; \
      const float cc_ = sigm(gv[1]) * c0[r] + sigm(gv[0]) * tanh_(gv[2]);      \
      c0[r] = cc_;                                                             \
      const float h_ = sigm(gv[3]) * tanh_(cc_);                               \
      h0_buf[NXT][(q * 4 + r) * HP + w * 16 + l15] = f2bf(h_);                 \
    }                                                                          \
    __syncthreads();  /* A: h0(S) visible */                                   \
    /* cell1: accB += W1ih x h0(S) */                                          \
    _Pragma("unroll")                                                          \
    for (int kt = 0; kt < 2; ++kt) {                                           \
      const bf16x8 af = *reinterpret_cast<const bf16x8*>(&h0_buf[NXT][l15 * HP + kt * 32 + q * 8]); \
      _Pragma("unroll")                                                        \
      for (int g = 0; g < 4; ++g) {                                            \
        const bf16x8 bl = *reinterpret_cast<const bf16x8*>(&w1lds[nofs[g] + kt * 32 + q * 8]); \
        accB[g] = MFMA16(af, bl, accB[g]);                                     \
      }                                                                        \
    }                                                                          \
    _Pragma("unroll")                                                          \
    for (int kt = 2; kt < 4; ++kt) {                                           \
      const bf16x8 af = *reinterpret_cast<const bf16x8*>(&h0_buf[NXT][l15 * HP + kt * 32 + q * 8]); \
      _Pragma("unroll")                                                        \
      for (int g = 0; g < 4; ++g) accB[g] = MFMA16(af, bw1[g][kt - 2], accB[g]); \
    }                                                                          \
    _Pragma("unroll")                                                          \
    for (int r = 0; r < 4; ++r) {                                              \
      const float i_ = accB[0][r], f_ = accB[1][r], g_ = accB[2][r], o_ = accB[3][r]; \
      const float cc_ = sigm(f_) * c1[r] + sigm(i_) * tanh_(g_);               \
      c1[r] = cc_;                                                             \
      const float h_ = sigm(o_) * tanh_(cc_);                                  \
      h1_buf[NXT][(q * 4 + r) * HP + w * 16 + l15] = f2bf(h_);                 \
    }                                                                          \
    __syncthreads();  /* B: h1(S) visible */                                   \
    /* out projection + feedback */                                            \
    {                                                                          \
      f32x4 p = {0.f, 0.f, 0.f, 0.f};                                          \
      _Pragma("unroll")                                                        \
      for (int kt = 0; kt < 4; ++kt) {                                         \
        const bf16x8 af = *reinterpret_cast<const bf16x8*>(&h1_buf[NXT][l15 * HP + kt * 32 + q * 8]); \
        p = MFMA16(af, owf[kt], p);                                            \
      }                                                                        \
      float pb[4];                                                             \
      _Pragma("unroll")                                                        \
      for (int r = 0; r < 4; ++r) pb[r] = p[r] + outb_s;                       \
      if (w == 0 && l15 < 3) {                                                 \
        _Pragma("unroll")                                                      \
        for (int r = 0; r < 4; ++r)                                            \
          out[((size_t)(bbase + q * 4 + r) * HORZ + (S)) * 3 + l15] = pb[r];   \
      }                                                                        \
      _Pragma("unroll")                                                        \
      for (int r = 0; r < 4; ++r)                                              \
        _Pragma("unroll")                                                      \
        for (int c = 0; c < 3; ++c)                                            \
          xr[r][c] = __shfl(pb[r], (q << 4) + c, 64);                          \
    }                                                                          \
    /* precompute cell0 h-part for S+1 */                                      \
    if ((S) + 1 < HORZ) {                                                      \
      _Pragma("unroll")                                                        \
      for (int g = 0; g < 4; ++g) {                                            \
        (ACC0N)[g][0] = bias0[g]; (ACC0N)[g][1] = bias0[g];                    \
        (ACC0N)[g][2] = bias0[g]; (ACC0N)[g][3] = bias0[g];                    \
      }                                                                        \
      _Pragma("unroll")                                                        \
      for (int kt = 0; kt < 2; ++kt) {                                         \
        const bf16x8 af = *reinterpret_cast<const bf16x8*>(&h0_buf[NXT][l15 * HP + kt * 32 + q * 8]); \
        _Pragma("unroll")                                                      \
        for (int g = 0; g < 4; ++g) {                                          \
          const bf16x8 bl = *reinterpret_cast<const bf16x8*>(&w0lds[nofs[g] + kt * 32 + q * 8]); \
          (ACC0N)[g] = MFMA16(af, bl, (ACC0N)[g]);                             \
        }                                                                      \
      }                                                                        \
      _Pragma("unroll")                                                        \
      for (int kt = 2; kt < 4; ++kt) {                                         \
        const bf16x8 af = *reinterpret_cast<const bf16x8*>(&h0_buf[NXT][l15 * HP + kt * 32 + q * 8]); \
        _Pragma("unroll")                                                      \
        for (int g = 0; g < 4; ++g) (ACC0N)[g] = MFMA16(af, bw0[g][kt - 2], (ACC0N)[g]); \
      }                                                                        \
    }                                                                          \
  }

__global__ __launch_bounds__(512, 2)
void decoder_kernel(const float* __restrict__ dech, const float* __restrict__ decc,
                    const float* __restrict__ W0ih, const float* __restrict__ W0hh,
                    const float* __restrict__ b0ih, const float* __restrict__ b0hh,
                    const float* __restrict__ W1ih, const float* __restrict__ W1hh,
                    const float* __restrict__ b1ih, const float* __restrict__ b1hh,
                    const float* __restrict__ outW, const float* __restrict__ outb,
                    const float* __restrict__ stok,
                    float* __restrict__ out)
{
  __shared__ __align__(16) unsigned short w0lds[GD * WLP];   // W0hh k0..63
  __shared__ __align__(16) unsigned short w1lds[GD * WLP];   // W1ih k0..63
  __shared__ __align__(16) unsigned short h0_buf[2][BT * HP];
  __shared__ __align__(16) unsigned short h1_buf[2][BT * HP];

  const int tid  = threadIdx.x;
  const int lane = tid & 63;
  const int w    = tid >> 6;      // 0..7
  const int l15  = lane & 15;
  const int q    = lane >> 4;
  const int bbase = blockIdx.x * BT;

  for (int i = tid; i < GD * 8; i += 512) {
    const int n = i >> 3, c8 = i & 7;
    *reinterpret_cast<bf16x8*>(&w0lds[n * WLP + c8 * 8]) = cvt8(W0hh + n * HD + c8 * 8);
    *reinterpret_cast<bf16x8*>(&w1lds[n * WLP + c8 * 8]) = cvt8(W1ih + n * HD + c8 * 8);
  }

  bf16x8 bw0[4][2];    // W0hh k64..127
  bf16x8 bw1[4][6];    // W1ih k64..127 (2) + W1hh k0..127 (4)
  float  xw0[4][3], bias0[4], bias1[4];
  int    nofs[4];
  #pragma unroll
  for (int g = 0; g < 4; ++g) {
    const int n = g * 128 + w * 16 + l15;
    nofs[g] = n * WLP;
    #pragma unroll
    for (int kt = 2; kt < 4; ++kt) {
      bw0[g][kt - 2] = cvt8(W0hh + n * HD + kt * 32 + q * 8);
      bw1[g][kt - 2] = cvt8(W1ih + n * HD + kt * 32 + q * 8);
    }
    #pragma unroll
    for (int kt = 4; kt < 8; ++kt)
      bw1[g][kt - 2] = cvt8(W1hh + n * HD + (kt - 4) * 32 + q * 8);
    #pragma unroll
    for (int k = 0; k < 3; ++k) xw0[g][k] = W0ih[n * 3 + k];
    bias0[g] = b0ih[n] + b0hh[n];
    bias1[g] = b1ih[n] + b1hh[n];
  }

  bf16x8 owf[4];
  float outb_s = 0.f;
  {
    bf16x8 z;
    #pragma unroll
    for (int i = 0; i < 8; ++i) z[i] = 0;
    #pragma unroll
    for (int kt = 0; kt < 4; ++kt) owf[kt] = z;
    if (l15 < 3) {
      #pragma unroll
      for (int kt = 0; kt < 4; ++kt) owf[kt] = cvt8(outW + l15 * HD + kt * 32 + q * 8);
      outb_s = outb[l15];
    }
  }

  float c0[4], c1[4];
  #pragma unroll
  for (int r = 0; r < 4; ++r) {
    const int b   = bbase + q * 4 + r;
    const int cix = w * 16 + l15;
    c0[r] = decc[b * HD + cix];
    c1[r] = decc[(NB + b) * HD + cix];
  }
  for (int i = tid; i < BT * HD; i += 512) {
    const int b = i >> 7, cix = i & 127;
    h0_buf[0][b * HP + cix] = f2bf(dech[(bbase + b) * HD + cix]);
    h1_buf[0][b * HP + cix] = f2bf(dech[(NB + bbase + b) * HD + cix]);
  }
  float xr[4][3];
  {
    const float s0 = stok[0], s1 = stok[1], s2 = stok[2];
    #pragma unroll
    for (int r = 0; r < 4; ++r) { xr[r][0] = s0; xr[r][1] = s1; xr[r][2] = s2; }
  }
  __syncthreads();

  // prologue: cell0 h-part for step 0 from h0_buf[0]
  f32x4 acc0P[4], acc0Q[4];
  #pragma unroll
  for (int g = 0; g < 4; ++g) {
    acc0P[g][0] = bias0[g]; acc0P[g][1] = bias0[g];
    acc0P[g][2] = bias0[g]; acc0P[g][3] = bias0[g];
  }
  #pragma unroll
  for (int kt = 0; kt < 2; ++kt) {
    const bf16x8 af = *reinterpret_cast<const bf16x8*>(&h0_buf[0][l15 * HP + kt * 32 + q * 8]);
    #pragma unroll
    for (int g = 0; g < 4; ++g) {
      const bf16x8 bl = *reinterpret_cast<const bf16x8*>(&w0lds[nofs[g] + kt * 32 + q * 8]);
      acc0P[g] = MFMA16(af, bl, acc0P[g]);
    }
  }
  #pragma unroll
  for (int kt = 2; kt < 4; ++kt) {
    const bf16x8 af = *reinterpret_cast<const bf16x8*>(&h0_buf[0][l15 * HP + kt * 32 + q * 8]);
    #pragma unroll
    for (int g = 0; g < 4; ++g) acc0P[g] = MFMA16(af, bw0[g][kt - 2], acc0P[g]);
  }

  for (int m = 0; m < HORZ / 2; ++m) {
    const int s0 = 2 * m;
    DEC_BODY(s0,     0, 1, acc0P, acc0Q)
    DEC_BODY(s0 + 1, 1, 0, acc0Q, acc0P)
  }
}

// ---------------------------------------------------------------------------
extern "C" void kernel_launch(void* const* d_in, const int* in_sizes, int n_in,
                              void* d_out, int out_size, void* d_ws, size_t ws_size,
                              hipStream_t stream)
{
  (void)in_sizes; (void)n_in; (void)out_size; (void)ws_size;
  const float* x      = (const float*)d_in[0];
  const float* e0fWih = (const float*)d_in[1];
  const float* e0fWhh = (const float*)d_in[2];
  const float* e0fbih = (const float*)d_in[3];
  const float* e0fbhh = (const float*)d_in[4];
  const float* e0bWih = (const float*)d_in[5];
  const float* e0bWhh = (const float*)d_in[6];
  const float* e0bbih = (const float*)d_in[7];
  const float* e0bbhh = (const float*)d_in[8];
  const float* e1fWih = (const float*)d_in[9];
  const float* e1fWhh = (const float*)d_in[10];
  const float* e1fbih = (const float*)d_in[11];
  const float* e1fbhh = (const float*)d_in[12];
  const float* e1bWih = (const float*)d_in[13];
  const float* e1bWhh = (const float*)d_in[14];
  const float* e1bbih = (const float*)d_in[15];
  const float* e1bbhh = (const float*)d_in[16];
  const float* brhW   = (const float*)d_in[17];
  const float* brhb   = (const float*)d_in[18];
  const float* brcW   = (const float*)d_in[19];
  const float* brcb   = (const float*)d_in[20];
  const float* d0Wih  = (const float*)d_in[21];
  const float* d0Whh  = (const float*)d_in[22];
  const float* d0bih  = (const float*)d_in[23];
  const float* d0bhh  = (const float*)d_in[24];
  const float* d1Wih  = (const float*)d_in[25];
  const float* d1Whh  = (const float*)d_in[26];
  const float* d1bih  = (const float*)d_in[27];
  const float* d1bhh  = (const float*)d_in[28];
  const float* outW   = (const float*)d_in[29];
  const float* outb   = (const float*)d_in[30];
  const float* stok   = (const float*)d_in[31];

  char* ws = (char*)d_ws;
  unsigned short* y0 = (unsigned short*)ws;                        // internal bf16
  size_t off = (size_t)NB * T_SEQ * 256 * sizeof(unsigned short);  // 188.7 MB
  const size_t blk = (size_t)2 * NB * HD * sizeof(float);          // 512 KB each
  float* ench0 = (float*)(ws + off); off += blk;
  float* encc0 = (float*)(ws + off); off += blk;
  float* ench1 = (float*)(ws + off); off += blk;
  float* encc1 = (float*)(ws + off); off += blk;
  float* dech  = (float*)(ws + off); off += blk;
  float* decc  = (float*)(ws + off); off += blk;

  enc_layer0_kernel<<<dim3(64), dim3(512), 0, stream>>>(
      x, e0fWih, e0fWhh, e0fbih, e0fbhh, e0bWih, e0bWhh, e0bbih, e0bbhh,
      y0, ench0, encc0);
  enc_layer1_kernel<<<dim3(64), dim3(512), 0, stream>>>(
      y0, e1fWih, e1fWhh, e1fbih, e1fbhh, e1bWih, e1bWhh, e1bbih, e1bbhh,
      ench1, encc1);
  bridge_kernel<<<dim3(1024), dim3(256), 0, stream>>>(
      ench0, encc0, ench1, encc1, brhW, brhb, brcW, brcb, dech, decc);
  decoder_kernel<<<dim3(32), dim3(512), 0, stream>>>(
      dech, decc, d0Wih, d0Whh, d0bih, d0bhh, d1Wih, d1Whh, d1bih, d1bhh,
      outW, outb, stok, (float*)d_out);
}

// Round 8
// 3146.423 us; speedup vs baseline: 1.1440x; 1.1272x over previous
//
#include <hip/hip_runtime.h>

typedef __attribute__((ext_vector_type(8))) short bf16x8;
typedef __attribute__((ext_vector_type(4))) float f32x4;

#define MFMA16(a,b,c) __builtin_amdgcn_mfma_f32_16x16x32_bf16((a),(b),(c),0,0,0)

#define T_SEQ  720
#define NB     512
#define HD     128
#define GD     512
#define BT     16
#define HP     136   // h row stride: 68 words % 32 banks = 4 -> 2-way (free)
#define HP0    168   // enc0 row: 128 h + 6 xhi + 6 xlo + 20 zero + 8 pad
#define YT     256   // UNPADDED y0-tile row (XOR-swizzled image, global_load_lds target)
#define WLP    68    // LDS weight row stride (64 k + 4 pad): 34 words -> 2-way (free)
#define HORZ   360

__device__ __forceinline__ float bf2f_(unsigned short u){
  union { unsigned int i; float f; } v; v.i = ((unsigned int)u) << 16; return v.f;
}
__device__ __forceinline__ unsigned short f2bf(float f){
  union { float f; unsigned int i; } v; v.f = f;
  unsigned int r = v.i + 0x7fffu + ((v.i >> 16) & 1u);
  return (unsigned short)(r >> 16);
}
__device__ __forceinline__ float rcp_(float x){ return __builtin_amdgcn_rcpf(x); }
__device__ __forceinline__ float sigm(float x){ return rcp_(1.f + __expf(-x)); }
// tanh(x) = 2*sigm(2x) - 1 : 5 VALU inst, branch-free, saturates cleanly
__device__ __forceinline__ float tanh_(float x){
  return __builtin_fmaf(2.f, rcp_(1.f + __expf(-2.f * x)), -1.f);
}
__device__ __forceinline__ bf16x8 cvt8(const float* p){
  bf16x8 r;
  #pragma unroll
  for (int i = 0; i < 8; ++i) r[i] = (short)f2bf(p[i]);
  return r;
}
// async global->LDS, 16B/lane; LDS dest = wave-uniform base + lane*16
__device__ __forceinline__ void gl_lds16(const unsigned short* g, unsigned short* l){
  __builtin_amdgcn_global_load_lds(
      (const __attribute__((address_space(1))) void*)(g),
      (__attribute__((address_space(3))) void*)(l), 16, 0, 0);
}

// ---------------------------------------------------------------------------
// Encoder layer 0 (bidirectional): 64 WGs x 512 thr. Single barrier/step,
// h ping-pong, K=160 MFMA folds x (hi/lo bf16 split). (R4 config.)
// ---------------------------------------------------------------------------
__global__ __launch_bounds__(512, 2)
void enc_layer0_kernel(const float* __restrict__ x,
                       const float* __restrict__ WihF, const float* __restrict__ WhhF,
                       const float* __restrict__ bihF, const float* __restrict__ bhhF,
                       const float* __restrict__ WihB, const float* __restrict__ WhhB,
                       const float* __restrict__ bihB, const float* __restrict__ bhhB,
                       unsigned short* __restrict__ y0,
                       float* __restrict__ ench, float* __restrict__ encc)
{
  __shared__ __align__(16) unsigned short h_buf[2][BT * HP0];
  const int tid  = threadIdx.x;
  const int lane = tid & 63;
  const int w    = tid >> 6;      // 0..7
  const int l15  = lane & 15;
  const int q    = lane >> 4;
  const int dir  = blockIdx.x >> 5;
  const int bbase = (blockIdx.x & 31) * BT;

  const float* Wih = dir ? WihB : WihF;
  const float* Whh = dir ? WhhB : WhhF;
  const float* bih = dir ? bihB : bihF;
  const float* bhh = dir ? bhhB : bhhF;

  bf16x8 bw[4][5];          // per gate: Whh kt0..3 + x-fold kt4
  f32x4  bias_vec[4];
  #pragma unroll
  for (int g = 0; g < 4; ++g) {
    const int n = g * 128 + w * 16 + l15;
    #pragma unroll
    for (int kt = 0; kt < 4; ++kt)
      bw[g][kt] = cvt8(Whh + n * HD + kt * 32 + q * 8);
    bf16x8 f;
    #pragma unroll
    for (int j = 0; j < 8; ++j) {
      const int kk = q * 8 + j;                 // col 128+kk
      float wv = 0.f;
      if (kk < 6)       wv = Wih[n * 6 + kk];        // x-hi cols
      else if (kk < 12) wv = Wih[n * 6 + (kk - 6)];  // x-lo cols
      f[j] = (short)f2bf(wv);
    }
    bw[g][4] = f;
    const float b = bih[n] + bhh[n];
    bias_vec[g][0] = b; bias_vec[g][1] = b; bias_vec[g][2] = b; bias_vec[g][3] = b;
  }

  int t = dir ? (T_SEQ - 1) : 0;
  const int dt = dir ? -1 : 1;
  const int xr_ = tid / 6, xk_ = tid % 6;       // valid for tid<96

  float cst[4] = {0.f, 0.f, 0.f, 0.f};
  for (int i = tid; i < 2 * BT * HP0; i += 512) (&h_buf[0][0])[i] = 0;
  __syncthreads();  // zeros visible before x-col writes
  float xv_cur = 0.f;
  if (tid < 96) {   // x(t0) -> buf0 ; preload x(t1)
    const float v0 = x[((size_t)(bbase + xr_) * T_SEQ + t) * 6 + xk_];
    const unsigned short hi = f2bf(v0);
    h_buf[0][xr_ * HP0 + 128 + xk_] = hi;
    h_buf[0][xr_ * HP0 + 134 + xk_] = f2bf(v0 - bf2f_(hi));
    xv_cur = x[((size_t)(bbase + xr_) * T_SEQ + t + dt) * 6 + xk_];
  }
  __syncthreads();

  for (int s = 0; s < T_SEQ; ++s, t += dt) {
    const int cur = s & 1, nxt = cur ^ 1;

    if (s > 0 && tid < 256) {   // y0 store for h(s-1); drains during compute
      const int b = tid >> 4, c8 = tid & 15;
      const bf16x8 hv = *reinterpret_cast<const bf16x8*>(&h_buf[cur][b * HP0 + c8 * 8]);
      *reinterpret_cast<bf16x8*>(y0 + ((size_t)(bbase + b) * T_SEQ + (t - dt)) * 256 + dir * HD + c8 * 8) = hv;
    }
    float xv_next = 0.f;
    if (tid < 96 && s + 2 < T_SEQ)
      xv_next = x[((size_t)(bbase + xr_) * T_SEQ + (t + 2 * dt)) * 6 + xk_];

    f32x4 acc[4];
    #pragma unroll
    for (int kt = 0; kt < 5; ++kt) {
      const bf16x8 af = *reinterpret_cast<const bf16x8*>(&h_buf[cur][l15 * HP0 + kt * 32 + q * 8]);
      #pragma unroll
      for (int g = 0; g < 4; ++g)
        acc[g] = MFMA16(af, bw[g][kt], kt == 0 ? bias_vec[g] : acc[g]);
    }

    #pragma unroll
    for (int r = 0; r < 4; ++r) {
      const float i_ = acc[0][r], f_ = acc[1][r], g_ = acc[2][r], o_ = acc[3][r];
      const float c_ = sigm(f_) * cst[r] + sigm(i_) * tanh_(g_);
      cst[r] = c_;
      const float h_ = sigm(o_) * tanh_(c_);
      h_buf[nxt][(q * 4 + r) * HP0 + w * 16 + l15] = f2bf(h_);
      if (s == T_SEQ - 1) {
        const int b   = bbase + q * 4 + r;
        const int cix = w * 16 + l15;
        ench[(dir * NB + b) * HD + cix] = h_;
        encc[(dir * NB + b) * HD + cix] = c_;
      }
    }
    if (tid < 96 && s + 1 < T_SEQ) {   // x(s+1) -> buf[nxt]
      const unsigned short hi = f2bf(xv_cur);
      h_buf[nxt][xr_ * HP0 + 128 + xk_] = hi;
      h_buf[nxt][xr_ * HP0 + 134 + xk_] = f2bf(xv_cur - bf2f_(hi));
    }
    xv_cur = xv_next;
    __syncthreads();   // single barrier: nxt visible, cur free
  }
  if (tid < 256) {   // final y0 store
    const int cur = T_SEQ & 1;
    const int b = tid >> 4, c8 = tid & 15;
    const bf16x8 hv = *reinterpret_cast<const bf16x8*>(&h_buf[cur][b * HP0 + c8 * 8]);
    const int tl = dir ? 0 : (T_SEQ - 1);
    *reinterpret_cast<bf16x8*>(y0 + ((size_t)(bbase + b) * T_SEQ + tl) * 256 + dir * HD + c8 * 8) = hv;
  }
}

// ---------------------------------------------------------------------------
// Encoder layer 1 (PIPELINED, R7 structure): y-part precomputed a step ahead,
// triple-buffered async y0 tiles, single barrier/step.
// ---------------------------------------------------------------------------
#define ENC1_YPART(ACC, YB)                                                    \
  {                                                                            \
    _Pragma("unroll")                                                          \
    for (int g = 0; g < 4; ++g) {                                              \
      (ACC)[g][0] = bias[g]; (ACC)[g][1] = bias[g];                            \
      (ACC)[g][2] = bias[g]; (ACC)[g][3] = bias[g];                            \
    }                                                                          \
    _Pragma("unroll")                                                          \
    for (int kt = 0; kt < 2; ++kt) {                                           \
      const int swz_ = ((kt * 4 + q) & 15) ^ l15;                              \
      const bf16x8 af = *reinterpret_cast<const bf16x8*>(&(YB)[l15 * YT + swz_ * 8]); \
      _Pragma("unroll")                                                        \
      for (int g = 0; g < 4; ++g) {                                            \
        const bf16x8 bl = *reinterpret_cast<const bf16x8*>(&wlds[nofs[g] + kt * 32 + q * 8]); \
        (ACC)[g] = MFMA16(af, bl, (ACC)[g]);                                   \
      }                                                                        \
    }                                                                          \
    _Pragma("unroll")                                                          \
    for (int kt = 2; kt < 8; ++kt) {                                           \
      const int c_ = kt * 4 + q;                                               \
      const int swz_ = (c_ & 16) | ((c_ & 15) ^ l15);                          \
      const bf16x8 af = *reinterpret_cast<const bf16x8*>(&(YB)[l15 * YT + swz_ * 8]); \
      _Pragma("unroll")                                                        \
      for (int g = 0; g < 4; ++g) (ACC)[g] = MFMA16(af, bw[g][kt - 2], (ACC)[g]); \
    }                                                                          \
  }

#define ENC1_BODY(S, CUR, NXT, ACCC, ACCN)                                     \
  {                                                                            \
    if ((S) + 2 < T_SEQ)                                                       \
      gl_lds16(y0 + grow + (size_t)(t + 2 * dt) * 256, b2 + w * 512);          \
    _Pragma("unroll")                                                          \
    for (int kt = 8; kt < 12; ++kt) {                                          \
      const bf16x8 af = *reinterpret_cast<const bf16x8*>(&h_buf[CUR][l15 * HP + (kt - 8) * 32 + q * 8]); \
      _Pragma("unroll")                                                        \
      for (int g = 0; g < 4; ++g) (ACCC)[g] = MFMA16(af, bw[g][kt - 2], (ACCC)[g]); \
    }                                                                          \
    if ((S) + 1 < T_SEQ) ENC1_YPART(ACCN, b1)                                  \
    _Pragma("unroll")                                                          \
    for (int r = 0; r < 4; ++r) {                                              \
      const float i_ = (ACCC)[0][r], f_ = (ACCC)[1][r];                        \
      const float g_ = (ACCC)[2][r], o_ = (ACCC)[3][r];                        \
      const float cc_ = sigm(f_) * cst[r] + sigm(i_) * tanh_(g_);              \
      cst[r] = cc_;                                                            \
      const float h_ = sigm(o_) * tanh_(cc_);                                  \
      h_buf[NXT][(q * 4 + r) * HP + w * 16 + l15] = f2bf(h_);                  \
      if ((S) == T_SEQ - 1) {                                                  \
        const int b_ = bbase + q * 4 + r;                                      \
        const int cix = w * 16 + l15;                                          \
        ench[(dir * NB + b_) * HD + cix] = h_;                                 \
        encc[(dir * NB + b_) * HD + cix] = cc_;                                \
      }                                                                        \
    }                                                                          \
    { unsigned short* tmp_ = b0; b0 = b1; b1 = b2; b2 = tmp_; }                \
    t += dt;                                                                   \
    __syncthreads();                                                           \
  }

__global__ __launch_bounds__(512, 2)
void enc_layer1_kernel(const unsigned short* __restrict__ y0,
                       const float* __restrict__ WihF, const float* __restrict__ WhhF,
                       const float* __restrict__ bihF, const float* __restrict__ bhhF,
                       const float* __restrict__ WihB, const float* __restrict__ WhhB,
                       const float* __restrict__ bihB, const float* __restrict__ bhhB,
                       float* __restrict__ ench, float* __restrict__ encc)
{
  __shared__ __align__(16) unsigned short wlds[GD * WLP];       // Wih k0..63
  __shared__ __align__(16) unsigned short ybuf[3][BT * YT];     // triple buffer
  __shared__ __align__(16) unsigned short h_buf[2][BT * HP];

  const int tid  = threadIdx.x;
  const int lane = tid & 63;
  const int w    = tid >> 6;      // 0..7
  const int l15  = lane & 15;
  const int q    = lane >> 4;
  const int dir  = blockIdx.x >> 5;
  const int bbase = (blockIdx.x & 31) * BT;

  const float* Wih = dir ? WihB : WihF;
  const float* Whh = dir ? WhhB : WhhF;
  const float* bih = dir ? bihB : bihF;
  const float* bhh = dir ? bhhB : bhhF;

  for (int i = tid; i < GD * 8; i += 512) {
    const int n = i >> 3, c8 = i & 7;
    *reinterpret_cast<bf16x8*>(&wlds[n * WLP + c8 * 8]) = cvt8(Wih + n * 256 + c8 * 8);
  }

  bf16x8 bw[4][10];   // kt2..7: Wih k64..255 ; kt8..11: Whh k0..127
  float  bias[4];
  int    nofs[4];
  #pragma unroll
  for (int g = 0; g < 4; ++g) {
    const int n = g * 128 + w * 16 + l15;
    nofs[g] = n * WLP;
    #pragma unroll
    for (int kt = 2; kt < 8; ++kt)  bw[g][kt - 2] = cvt8(Wih + n * 256 + kt * 32 + q * 8);
    #pragma unroll
    for (int kt = 8; kt < 12; ++kt) bw[g][kt - 2] = cvt8(Whh + n * HD + (kt - 8) * 32 + q * 8);
    bias[g] = bih[n] + bhh[n];
  }

  const int sb   = 2 * w + (lane >> 5);         // batch row 0..15
  const int cimg = lane & 31;
  const int sig  = (cimg & 16) | ((cimg & 15) ^ (sb & 15));
  const size_t grow = (size_t)(bbase + sb) * T_SEQ * 256 + (size_t)sig * 8;
  unsigned short* b0 = &ybuf[0][0];
  unsigned short* b1 = &ybuf[1][0];
  unsigned short* b2 = &ybuf[2][0];

  int t = dir ? (T_SEQ - 1) : 0;
  const int dt = dir ? -1 : 1;

  float cst[4] = {0.f, 0.f, 0.f, 0.f};
  for (int i = tid; i < 2 * BT * HP; i += 512) (&h_buf[0][0])[i] = 0;
  gl_lds16(y0 + grow + (size_t)t * 256,        b0 + w * 512);   // tile 0
  gl_lds16(y0 + grow + (size_t)(t + dt) * 256, b1 + w * 512);   // tile 1
  __syncthreads();                                               // drains vmcnt

  f32x4 accP[4], accQ[4];
  ENC1_YPART(accP, b0)   // y0-partial for step 0

  for (int m = 0; m < T_SEQ / 2; ++m) {
    const int s0 = 2 * m;
    ENC1_BODY(s0,     0, 1, accP, accQ)
    ENC1_BODY(s0 + 1, 1, 0, accQ, accP)
  }
}

// ---------------------------------------------------------------------------
// Bridge: h_dec = h_enc @ brh_W.T + brh_b ; same for c with brc. Pure fp32.
// ---------------------------------------------------------------------------
__global__ void bridge_kernel(const float* __restrict__ ench0, const float* __restrict__ encc0,
                              const float* __restrict__ ench1, const float* __restrict__ encc1,
                              const float* __restrict__ brhW, const float* __restrict__ brhb,
                              const float* __restrict__ brcW, const float* __restrict__ brcb,
                              float* __restrict__ dech, float* __restrict__ decc)
{
  const int idx = blockIdx.x * 256 + threadIdx.x;   // 262144 total
  const int sel = idx >> 17;          // 0: h, 1: c
  const int l   = (idx >> 16) & 1;    // layer
  const int b   = (idx >> 7) & 511;
  const int j   = idx & 127;
  const float* W  = sel ? brcW : brhW;
  const float* bb = sel ? brcb : brhb;
  const float* s0 = sel ? (l ? encc1 : encc0) : (l ? ench1 : ench0);
  float a = bb[j];
  for (int k = 0; k < 128; ++k) a += W[j * 256 + k] * s0[b * 128 + k];
  for (int k = 0; k < 128; ++k) a += W[j * 256 + 128 + k] * s0[(512 + b) * 128 + k];
  float* dst = sel ? decc : dech;
  dst[(l * 512 + b) * 128 + j] = a;
}

// ---------------------------------------------------------------------------
// Decoder: R4 skeleton (2 barriers, W0hh/W1ih k0..63 in LDS) + VALU-lean
// feedback: pred computed redundantly per wave, staged into per-wave LDS
// x-region (no barrier, no shfl), consumed as one extra MFMA K-tile.
// W1hh x h1(s-1) precomputed in phase A. Fast-tanh throughout.
// ---------------------------------------------------------------------------
__global__ __launch_bounds__(512, 2)
void decoder_kernel(const float* __restrict__ dech, const float* __restrict__ decc,
                    const float* __restrict__ W0ih, const float* __restrict__ W0hh,
                    const float* __restrict__ b0ih, const float* __restrict__ b0hh,
                    const float* __restrict__ W1ih, const float* __restrict__ W1hh,
                    const float* __restrict__ b1ih, const float* __restrict__ b1hh,
                    const float* __restrict__ outW, const float* __restrict__ outb,
                    const float* __restrict__ stok,
                    float* __restrict__ out)
{
  __shared__ __align__(16) unsigned short w0lds[GD * WLP];   // W0hh k0..63
  __shared__ __align__(16) unsigned short w1lds[GD * WLP];   // W1ih k0..63
  __shared__ __align__(16) unsigned short h0_buf[2][BT * HP];
  __shared__ __align__(16) unsigned short h1_buf[2][BT * HP];
  __shared__ __align__(16) unsigned short xstage[8][BT * 8]; // per-wave pred rows
  __shared__ __align__(16) unsigned short xzero[8];          // shared zero frag

  const int tid  = threadIdx.x;
  const int lane = tid & 63;
  const int w    = tid >> 6;      // 0..7
  const int l15  = lane & 15;
  const int q    = lane >> 4;
  const int bbase = blockIdx.x * BT;

  for (int i = tid; i < GD * 8; i += 512) {
    const int n = i >> 3, c8 = i & 7;
    *reinterpret_cast<bf16x8*>(&w0lds[n * WLP + c8 * 8]) = cvt8(W0hh + n * HD + c8 * 8);
    *reinterpret_cast<bf16x8*>(&w1lds[n * WLP + c8 * 8]) = cvt8(W1ih + n * HD + c8 * 8);
  }

  bf16x8 bw0[4][2];    // W0hh k64..127
  bf16x8 bw1[4][6];    // W1ih k64..127 (2) + W1hh k0..127 (4)
  bf16x8 wx0[4];       // W0ih as x-fold K-tile (cols 0..2 live)
  f32x4  bias0_vec[4], bias1_vec[4];
  int    nofs[4];
  #pragma unroll
  for (int g = 0; g < 4; ++g) {
    const int n = g * 128 + w * 16 + l15;
    nofs[g] = n * WLP;
    #pragma unroll
    for (int kt = 2; kt < 4; ++kt) {
      bw0[g][kt - 2] = cvt8(W0hh + n * HD + kt * 32 + q * 8);
      bw1[g][kt - 2] = cvt8(W1ih + n * HD + kt * 32 + q * 8);
    }
    #pragma unroll
    for (int kt = 4; kt < 8; ++kt)
      bw1[g][kt - 2] = cvt8(W1hh + n * HD + (kt - 4) * 32 + q * 8);
    bf16x8 f;
    #pragma unroll
    for (int j = 0; j < 8; ++j) {
      const int kk = q * 8 + j;
      f[j] = (short)((kk < 3) ? f2bf(W0ih[n * 3 + kk]) : 0);
    }
    wx0[g] = f;
    const float b0 = b0ih[n] + b0hh[n];
    const float b1 = b1ih[n] + b1hh[n];
    bias0_vec[g][0] = b0; bias0_vec[g][1] = b0; bias0_vec[g][2] = b0; bias0_vec[g][3] = b0;
    bias1_vec[g][0] = b1; bias1_vec[g][1] = b1; bias1_vec[g][2] = b1; bias1_vec[g][3] = b1;
  }

  bf16x8 owf[4];       // out-projection fragments, all waves (redundant)
  float outb_s = 0.f;
  {
    bf16x8 z;
    #pragma unroll
    for (int i = 0; i < 8; ++i) z[i] = 0;
    #pragma unroll
    for (int kt = 0; kt < 4; ++kt) owf[kt] = z;
    if (l15 < 3) {
      #pragma unroll
      for (int kt = 0; kt < 4; ++kt) owf[kt] = cvt8(outW + l15 * HD + kt * 32 + q * 8);
      outb_s = outb[l15];
    }
  }

  float c0[4], c1[4];
  #pragma unroll
  for (int r = 0; r < 4; ++r) {
    const int b   = bbase + q * 4 + r;
    const int cix = w * 16 + l15;
    c0[r] = decc[b * HD + cix];
    c1[r] = decc[(NB + b) * HD + cix];
  }
  for (int i = tid; i < BT * HD; i += 512) {
    const int b = i >> 7, cix = i & 127;
    h0_buf[0][b * HP + cix] = f2bf(dech[(bbase + b) * HD + cix]);
    h1_buf[0][b * HP + cix] = f2bf(dech[(NB + bbase + b) * HD + cix]);
  }
  // xstage init: rows 0..15 x cols 0..7 per wave; cols 0..2 = stok, rest 0
  {
    const int row = lane >> 2, col = lane & 3;          // 16x4 over 64 lanes
    const unsigned short v = (col < 3) ? f2bf(stok[col]) : 0;
    xstage[w][row * 8 + col] = v;
    xstage[w][row * 8 + 4 + col] = 0;
    if (tid < 8) xzero[tid] = 0;
  }
  // per-lane A-frag pointer for the x K-tile: q==0 reads its row, else zeros
  const unsigned short* afx_ptr = (q == 0) ? &xstage[w][l15 * 8] : xzero;
  __syncthreads();

  for (int s = 0; s < HORZ; ++s) {
    const int cur = s & 1, nxt = cur ^ 1;

    // ---- phase A ----------------------------------------------------------
    // shadow for phase B: accC = bias1 + W1hh x h1(s-1)
    f32x4 accC[4];
    #pragma unroll
    for (int kt = 4; kt < 8; ++kt) {
      const bf16x8 af = *reinterpret_cast<const bf16x8*>(&h1_buf[cur][l15 * HP + (kt - 4) * 32 + q * 8]);
      #pragma unroll
      for (int g = 0; g < 4; ++g)
        accC[g] = MFMA16(af, bw1[g][kt - 2], kt == 4 ? bias1_vec[g] : accC[g]);
    }
    // out-projection of h1(s-1) -> pred(s-1), all waves redundant
    f32x4 p = {0.f, 0.f, 0.f, 0.f};
    #pragma unroll
    for (int kt = 0; kt < 4; ++kt) {
      const bf16x8 af = *reinterpret_cast<const bf16x8*>(&h1_buf[cur][l15 * HP + kt * 32 + q * 8]);
      p = MFMA16(af, owf[kt], p);
    }
    // cell0 h-part: acc0 = bias0 + W0hh x h0(s-1)
    f32x4 acc0[4];
    #pragma unroll
    for (int kt = 0; kt < 2; ++kt) {
      const bf16x8 af = *reinterpret_cast<const bf16x8*>(&h0_buf[cur][l15 * HP + kt * 32 + q * 8]);
      #pragma unroll
      for (int g = 0; g < 4; ++g) {
        const bf16x8 bl = *reinterpret_cast<const bf16x8*>(&w0lds[nofs[g] + kt * 32 + q * 8]);
        acc0[g] = MFMA16(af, bl, kt == 0 ? bias0_vec[g] : acc0[g]);
      }
    }
    #pragma unroll
    for (int kt = 2; kt < 4; ++kt) {
      const bf16x8 af = *reinterpret_cast<const bf16x8*>(&h0_buf[cur][l15 * HP + kt * 32 + q * 8]);
      #pragma unroll
      for (int g = 0; g < 4; ++g) acc0[g] = MFMA16(af, bw0[g][kt - 2], acc0[g]);
    }
    // pred -> per-wave x-stage (same-wave write->read, no barrier needed)
    if (l15 < 3) {
      #pragma unroll
      for (int r = 0; r < 4; ++r) {
        const float v = p[r] + outb_s;
        xstage[w][(q * 4 + r) * 8 + l15] = f2bf(v);
        if (w == 0 && s > 0)
          out[((size_t)(bbase + q * 4 + r) * HORZ + (s - 1)) * 3 + l15] = v;
      }
    }
    // x K-tile onto acc0 (reads just-written stage)
    {
      const bf16x8 afx = *reinterpret_cast<const bf16x8*>(afx_ptr);
      #pragma unroll
      for (int g = 0; g < 4; ++g) acc0[g] = MFMA16(afx, wx0[g], acc0[g]);
    }
    // cell0 activation
    #pragma unroll
    for (int r = 0; r < 4; ++r) {
      const float i_ = acc0[0][r], f_ = acc0[1][r], g_ = acc0[2][r], o_ = acc0[3][r];
      const float c_ = sigm(f_) * c0[r] + sigm(i_) * tanh_(g_);
      c0[r] = c_;
      const float h_ = sigm(o_) * tanh_(c_);
      h0_buf[nxt][(q * 4 + r) * HP + w * 16 + l15] = f2bf(h_);
    }
    __syncthreads();   // barrier A: h0(s) visible

    // ---- phase B ----------------------------------------------------------
    #pragma unroll
    for (int kt = 0; kt < 2; ++kt) {
      const bf16x8 af = *reinterpret_cast<const bf16x8*>(&h0_buf[nxt][l15 * HP + kt * 32 + q * 8]);
      #pragma unroll
      for (int g = 0; g < 4; ++g) {
        const bf16x8 bl = *reinterpret_cast<const bf16x8*>(&w1lds[nofs[g] + kt * 32 + q * 8]);
        accC[g] = MFMA16(af, bl, accC[g]);
      }
    }
    #pragma unroll
    for (int kt = 2; kt < 4; ++kt) {
      const bf16x8 af = *reinterpret_cast<const bf16x8*>(&h0_buf[nxt][l15 * HP + kt * 32 + q * 8]);
      #pragma unroll
      for (int g = 0; g < 4; ++g) accC[g] = MFMA16(af, bw1[g][kt - 2], accC[g]);
    }
    #pragma unroll
    for (int r = 0; r < 4; ++r) {
      const float i_ = accC[0][r], f_ = accC[1][r], g_ = accC[2][r], o_ = accC[3][r];
      const float c_ = sigm(f_) * c1[r] + sigm(i_) * tanh_(g_);
      c1[r] = c_;
      const float h_ = sigm(o_) * tanh_(c_);
      h1_buf[nxt][(q * 4 + r) * HP + w * 16 + l15] = f2bf(h_);
    }
    __syncthreads();   // barrier B: h1(s) visible
  }

  // final pred(HORZ-1)
  {
    const int cur = HORZ & 1;
    f32x4 p = {0.f, 0.f, 0.f, 0.f};
    #pragma unroll
    for (int kt = 0; kt < 4; ++kt) {
      const bf16x8 af = *reinterpret_cast<const bf16x8*>(&h1_buf[cur][l15 * HP + kt * 32 + q * 8]);
      p = MFMA16(af, owf[kt], p);
    }
    if (w == 0 && l15 < 3) {
      #pragma unroll
      for (int r = 0; r < 4; ++r)
        out[((size_t)(bbase + q * 4 + r) * HORZ + (HORZ - 1)) * 3 + l15] = p[r] + outb_s;
    }
  }
}

// ---------------------------------------------------------------------------
extern "C" void kernel_launch(void* const* d_in, const int* in_sizes, int n_in,
                              void* d_out, int out_size, void* d_ws, size_t ws_size,
                              hipStream_t stream)
{
  (void)in_sizes; (void)n_in; (void)out_size; (void)ws_size;
  const float* x      = (const float*)d_in[0];
  const float* e0fWih = (const float*)d_in[1];
  const float* e0fWhh = (const float*)d_in[2];
  const float* e0fbih = (const float*)d_in[3];
  const float* e0fbhh = (const float*)d_in[4];
  const float* e0bWih = (const float*)d_in[5];
  const float* e0bWhh = (const float*)d_in[6];
  const float* e0bbih = (const float*)d_in[7];
  const float* e0bbhh = (const float*)d_in[8];
  const float* e1fWih = (const float*)d_in[9];
  const float* e1fWhh = (const float*)d_in[10];
  const float* e1fbih = (const float*)d_in[11];
  const float* e1fbhh = (const float*)d_in[12];
  const float* e1bWih = (const float*)d_in[13];
  const float* e1bWhh = (const float*)d_in[14];
  const float* e1bbih = (const float*)d_in[15];
  const float* e1bbhh = (const float*)d_in[16];
  const float* brhW   = (const float*)d_in[17];
  const float* brhb   = (const float*)d_in[18];
  const float* brcW   = (const float*)d_in[19];
  const float* brcb   = (const float*)d_in[20];
  const float* d0Wih  = (const float*)d_in[21];
  const float* d0Whh  = (const float*)d_in[22];
  const float* d0bih  = (const float*)d_in[23];
  const float* d0bhh  = (const float*)d_in[24];
  const float* d1Wih  = (const float*)d_in[25];
  const float* d1Whh  = (const float*)d_in[26];
  const float* d1bih  = (const float*)d_in[27];
  const float* d1bhh  = (const float*)d_in[28];
  const float* outW   = (const float*)d_in[29];
  const float* outb   = (const float*)d_in[30];
  const float* stok   = (const float*)d_in[31];

  char* ws = (char*)d_ws;
  unsigned short* y0 = (unsigned short*)ws;                        // internal bf16
  size_t off = (size_t)NB * T_SEQ * 256 * sizeof(unsigned short);  // 188.7 MB
  const size_t blk = (size_t)2 * NB * HD * sizeof(float);          // 512 KB each
  float* ench0 = (float*)(ws + off); off += blk;
  float* encc0 = (float*)(ws + off); off += blk;
  float* ench1 = (float*)(ws + off); off += blk;
  float* encc1 = (float*)(ws + off); off += blk;
  float* dech  = (float*)(ws + off); off += blk;
  float* decc  = (float*)(ws + off); off += blk;

  enc_layer0_kernel<<<dim3(64), dim3(512), 0, stream>>>(
      x, e0fWih, e0fWhh, e0fbih, e0fbhh, e0bWih, e0bWhh, e0bbih, e0bbhh,
      y0, ench0, encc0);
  enc_layer1_kernel<<<dim3(64), dim3(512), 0, stream>>>(
      y0, e1fWih, e1fWhh, e1fbih, e1fbhh, e1bWih, e1bWhh, e1bbih, e1bbhh,
      ench1, encc1);
  bridge_kernel<<<dim3(1024), dim3(256), 0, stream>>>(
      ench0, encc0, ench1, encc1, brhW, brhb, brcW, brcb, dech, decc);
  decoder_kernel<<<dim3(32), dim3(512), 0, stream>>>(
      dech, decc, d0Wih, d0Whh, d0bih, d0bhh, d1Wih, d1Whh, d1bih, d1bhh,
      outW, outb, stok, (float*)d_out);
}

// Round 9
// 2883.089 us; speedup vs baseline: 1.2485x; 1.0913x over previous
//
#include <hip/hip_runtime.h>

typedef __attribute__((ext_vector_type(8))) short bf16x8;
typedef __attribute__((ext_vector_type(4))) float f32x4;

#define MFMA16(a,b,c) __builtin_amdgcn_mfma_f32_16x16x32_bf16((a),(b),(c),0,0,0)

#define T_SEQ  720
#define NB     512
#define HD     128
#define GD     512
#define BT     16
#define HP     136   // h row stride: 68 words % 32 banks = 4 -> 2-way (free)
#define HP0    168   // enc0 row: 128 h + 6 xhi + 6 xlo + 20 zero + 8 pad
#define YT     256   // UNPADDED y0-tile row (XOR-swizzled image, global_load_lds target)
#define WLP    68    // LDS weight row stride (64 k + 4 pad): 34 words -> 2-way (free)
#define HORZ   360

__device__ __forceinline__ float bf2f_(unsigned short u){
  union { unsigned int i; float f; } v; v.i = ((unsigned int)u) << 16; return v.f;
}
__device__ __forceinline__ unsigned short f2bf(float f){
  union { float f; unsigned int i; } v; v.f = f;
  unsigned int r = v.i + 0x7fffu + ((v.i >> 16) & 1u);
  return (unsigned short)(r >> 16);
}
__device__ __forceinline__ float rcp_(float x){ return __builtin_amdgcn_rcpf(x); }
__device__ __forceinline__ float sigm(float x){ return rcp_(1.f + __expf(-x)); }
// tanh(x) = 2*sigm(2x) - 1 : 5 VALU inst, branch-free, saturates cleanly
__device__ __forceinline__ float tanh_(float x){
  return __builtin_fmaf(2.f, rcp_(1.f + __expf(-2.f * x)), -1.f);
}
__device__ __forceinline__ bf16x8 cvt8(const float* p){
  bf16x8 r;
  #pragma unroll
  for (int i = 0; i < 8; ++i) r[i] = (short)f2bf(p[i]);
  return r;
}
// async global->LDS, 16B/lane; LDS dest = wave-uniform base + lane*16
__device__ __forceinline__ void gl_lds16(const unsigned short* g, unsigned short* l){
  __builtin_amdgcn_global_load_lds(
      (const __attribute__((address_space(1))) void*)(g),
      (__attribute__((address_space(3))) void*)(l), 16, 0, 0);
}

// ---------------------------------------------------------------------------
// Encoder layer 0 (bidirectional): 64 WGs x 512 thr. Single barrier/step,
// h ping-pong, K=160 MFMA folds x (hi/lo bf16 split). (R4 structure.)
// ---------------------------------------------------------------------------
__global__ __launch_bounds__(512, 2)
void enc_layer0_kernel(const float* __restrict__ x,
                       const float* __restrict__ WihF, const float* __restrict__ WhhF,
                       const float* __restrict__ bihF, const float* __restrict__ bhhF,
                       const float* __restrict__ WihB, const float* __restrict__ WhhB,
                       const float* __restrict__ bihB, const float* __restrict__ bhhB,
                       unsigned short* __restrict__ y0,
                       float* __restrict__ ench, float* __restrict__ encc)
{
  __shared__ __align__(16) unsigned short h_buf[2][BT * HP0];
  const int tid  = threadIdx.x;
  const int lane = tid & 63;
  const int w    = tid >> 6;      // 0..7
  const int l15  = lane & 15;
  const int q    = lane >> 4;
  const int dir  = blockIdx.x >> 5;
  const int bbase = (blockIdx.x & 31) * BT;

  const float* Wih = dir ? WihB : WihF;
  const float* Whh = dir ? WhhB : WhhF;
  const float* bih = dir ? bihB : bihF;
  const float* bhh = dir ? bhhB : bhhF;

  bf16x8 bw[4][5];          // per gate: Whh kt0..3 + x-fold kt4
  f32x4  bias_vec[4];
  #pragma unroll
  for (int g = 0; g < 4; ++g) {
    const int n = g * 128 + w * 16 + l15;
    #pragma unroll
    for (int kt = 0; kt < 4; ++kt)
      bw[g][kt] = cvt8(Whh + n * HD + kt * 32 + q * 8);
    bf16x8 f;
    #pragma unroll
    for (int j = 0; j < 8; ++j) {
      const int kk = q * 8 + j;                 // col 128+kk
      float wv = 0.f;
      if (kk < 6)       wv = Wih[n * 6 + kk];        // x-hi cols
      else if (kk < 12) wv = Wih[n * 6 + (kk - 6)];  // x-lo cols
      f[j] = (short)f2bf(wv);
    }
    bw[g][4] = f;
    const float b = bih[n] + bhh[n];
    bias_vec[g][0] = b; bias_vec[g][1] = b; bias_vec[g][2] = b; bias_vec[g][3] = b;
  }

  int t = dir ? (T_SEQ - 1) : 0;
  const int dt = dir ? -1 : 1;
  const int xr_ = tid / 6, xk_ = tid % 6;       // valid for tid<96

  float cst[4] = {0.f, 0.f, 0.f, 0.f};
  for (int i = tid; i < 2 * BT * HP0; i += 512) (&h_buf[0][0])[i] = 0;
  __syncthreads();  // zeros visible before x-col writes
  float xv_cur = 0.f;
  if (tid < 96) {   // x(t0) -> buf0 ; preload x(t1)
    const float v0 = x[((size_t)(bbase + xr_) * T_SEQ + t) * 6 + xk_];
    const unsigned short hi = f2bf(v0);
    h_buf[0][xr_ * HP0 + 128 + xk_] = hi;
    h_buf[0][xr_ * HP0 + 134 + xk_] = f2bf(v0 - bf2f_(hi));
    xv_cur = x[((size_t)(bbase + xr_) * T_SEQ + t + dt) * 6 + xk_];
  }
  __syncthreads();

  for (int s = 0; s < T_SEQ; ++s, t += dt) {
    const int cur = s & 1, nxt = cur ^ 1;

    if (s > 0 && tid < 256) {   // y0 store for h(s-1); drains during compute
      const int b = tid >> 4, c8 = tid & 15;
      const bf16x8 hv = *reinterpret_cast<const bf16x8*>(&h_buf[cur][b * HP0 + c8 * 8]);
      *reinterpret_cast<bf16x8*>(y0 + ((size_t)(bbase + b) * T_SEQ + (t - dt)) * 256 + dir * HD + c8 * 8) = hv;
    }
    float xv_next = 0.f;
    if (tid < 96 && s + 2 < T_SEQ)
      xv_next = x[((size_t)(bbase + xr_) * T_SEQ + (t + 2 * dt)) * 6 + xk_];

    f32x4 acc[4];
    #pragma unroll
    for (int kt = 0; kt < 5; ++kt) {
      const bf16x8 af = *reinterpret_cast<const bf16x8*>(&h_buf[cur][l15 * HP0 + kt * 32 + q * 8]);
      #pragma unroll
      for (int g = 0; g < 4; ++g)
        acc[g] = MFMA16(af, bw[g][kt], kt == 0 ? bias_vec[g] : acc[g]);
    }

    #pragma unroll
    for (int r = 0; r < 4; ++r) {
      const float i_ = acc[0][r], f_ = acc[1][r], g_ = acc[2][r], o_ = acc[3][r];
      const float c_ = sigm(f_) * cst[r] + sigm(i_) * tanh_(g_);
      cst[r] = c_;
      const float h_ = sigm(o_) * tanh_(c_);
      h_buf[nxt][(q * 4 + r) * HP0 + w * 16 + l15] = f2bf(h_);
      if (s == T_SEQ - 1) {
        const int b   = bbase + q * 4 + r;
        const int cix = w * 16 + l15;
        ench[(dir * NB + b) * HD + cix] = h_;
        encc[(dir * NB + b) * HD + cix] = c_;
      }
    }
    if (tid < 96 && s + 1 < T_SEQ) {   // x(s+1) -> buf[nxt]
      const unsigned short hi = f2bf(xv_cur);
      h_buf[nxt][xr_ * HP0 + 128 + xk_] = hi;
      h_buf[nxt][xr_ * HP0 + 134 + xk_] = f2bf(xv_cur - bf2f_(hi));
    }
    xv_cur = xv_next;
    __syncthreads();   // single barrier: nxt visible, cur free
  }
  if (tid < 256) {   // final y0 store
    const int cur = T_SEQ & 1;
    const int b = tid >> 4, c8 = tid & 15;
    const bf16x8 hv = *reinterpret_cast<const bf16x8*>(&h_buf[cur][b * HP0 + c8 * 8]);
    const int tl = dir ? 0 : (T_SEQ - 1);
    *reinterpret_cast<bf16x8*>(y0 + ((size_t)(bbase + b) * T_SEQ + tl) * 256 + dir * HD + c8 * 8) = hv;
  }
}

// ---------------------------------------------------------------------------
// Encoder layer 1 (PIPELINED, R7/R8 structure): y-part precomputed a step
// ahead, triple-buffered async y0 tiles, single barrier/step.
// ---------------------------------------------------------------------------
#define ENC1_YPART(ACC, YB)                                                    \
  {                                                                            \
    _Pragma("unroll")                                                          \
    for (int g = 0; g < 4; ++g) {                                              \
      (ACC)[g][0] = bias[g]; (ACC)[g][1] = bias[g];                            \
      (ACC)[g][2] = bias[g]; (ACC)[g][3] = bias[g];                            \
    }                                                                          \
    _Pragma("unroll")                                                          \
    for (int kt = 0; kt < 2; ++kt) {                                           \
      const int swz_ = ((kt * 4 + q) & 15) ^ l15;                              \
      const bf16x8 af = *reinterpret_cast<const bf16x8*>(&(YB)[l15 * YT + swz_ * 8]); \
      _Pragma("unroll")                                                        \
      for (int g = 0; g < 4; ++g) {                                            \
        const bf16x8 bl = *reinterpret_cast<const bf16x8*>(&wlds[nofs[g] + kt * 32 + q * 8]); \
        (ACC)[g] = MFMA16(af, bl, (ACC)[g]);                                   \
      }                                                                        \
    }                                                                          \
    _Pragma("unroll")                                                          \
    for (int kt = 2; kt < 8; ++kt) {                                           \
      const int c_ = kt * 4 + q;                                               \
      const int swz_ = (c_ & 16) | ((c_ & 15) ^ l15);                          \
      const bf16x8 af = *reinterpret_cast<const bf16x8*>(&(YB)[l15 * YT + swz_ * 8]); \
      _Pragma("unroll")                                                        \
      for (int g = 0; g < 4; ++g) (ACC)[g] = MFMA16(af, bw[g][kt - 2], (ACC)[g]); \
    }                                                                          \
  }

#define ENC1_BODY(S, CUR, NXT, ACCC, ACCN)                                     \
  {                                                                            \
    if ((S) + 2 < T_SEQ)                                                       \
      gl_lds16(y0 + grow + (size_t)(t + 2 * dt) * 256, b2 + w * 512);          \
    _Pragma("unroll")                                                          \
    for (int kt = 8; kt < 12; ++kt) {                                          \
      const bf16x8 af = *reinterpret_cast<const bf16x8*>(&h_buf[CUR][l15 * HP + (kt - 8) * 32 + q * 8]); \
      _Pragma("unroll")                                                        \
      for (int g = 0; g < 4; ++g) (ACCC)[g] = MFMA16(af, bw[g][kt - 2], (ACCC)[g]); \
    }                                                                          \
    if ((S) + 1 < T_SEQ) ENC1_YPART(ACCN, b1)                                  \
    _Pragma("unroll")                                                          \
    for (int r = 0; r < 4; ++r) {                                              \
      const float i_ = (ACCC)[0][r], f_ = (ACCC)[1][r];                        \
      const float g_ = (ACCC)[2][r], o_ = (ACCC)[3][r];                        \
      const float cc_ = sigm(f_) * cst[r] + sigm(i_) * tanh_(g_);              \
      cst[r] = cc_;                                                            \
      const float h_ = sigm(o_) * tanh_(cc_);                                  \
      h_buf[NXT][(q * 4 + r) * HP + w * 16 + l15] = f2bf(h_);                  \
      if ((S) == T_SEQ - 1) {                                                  \
        const int b_ = bbase + q * 4 + r;                                      \
        const int cix = w * 16 + l15;                                          \
        ench[(dir * NB + b_) * HD + cix] = h_;                                 \
        encc[(dir * NB + b_) * HD + cix] = cc_;                                \
      }                                                                        \
    }                                                                          \
    { unsigned short* tmp_ = b0; b0 = b1; b1 = b2; b2 = tmp_; }                \
    t += dt;                                                                   \
    __syncthreads();                                                           \
  }

__global__ __launch_bounds__(512, 2)
void enc_layer1_kernel(const unsigned short* __restrict__ y0,
                       const float* __restrict__ WihF, const float* __restrict__ WhhF,
                       const float* __restrict__ bihF, const float* __restrict__ bhhF,
                       const float* __restrict__ WihB, const float* __restrict__ WhhB,
                       const float* __restrict__ bihB, const float* __restrict__ bhhB,
                       float* __restrict__ ench, float* __restrict__ encc)
{
  __shared__ __align__(16) unsigned short wlds[GD * WLP];       // Wih k0..63
  __shared__ __align__(16) unsigned short ybuf[3][BT * YT];     // triple buffer
  __shared__ __align__(16) unsigned short h_buf[2][BT * HP];

  const int tid  = threadIdx.x;
  const int lane = tid & 63;
  const int w    = tid >> 6;      // 0..7
  const int l15  = lane & 15;
  const int q    = lane >> 4;
  const int dir  = blockIdx.x >> 5;
  const int bbase = (blockIdx.x & 31) * BT;

  const float* Wih = dir ? WihB : WihF;
  const float* Whh = dir ? WhhB : WhhF;
  const float* bih = dir ? bihB : bihF;
  const float* bhh = dir ? bhhB : bhhF;

  for (int i = tid; i < GD * 8; i += 512) {
    const int n = i >> 3, c8 = i & 7;
    *reinterpret_cast<bf16x8*>(&wlds[n * WLP + c8 * 8]) = cvt8(Wih + n * 256 + c8 * 8);
  }

  bf16x8 bw[4][10];   // kt2..7: Wih k64..255 ; kt8..11: Whh k0..127
  float  bias[4];
  int    nofs[4];
  #pragma unroll
  for (int g = 0; g < 4; ++g) {
    const int n = g * 128 + w * 16 + l15;
    nofs[g] = n * WLP;
    #pragma unroll
    for (int kt = 2; kt < 8; ++kt)  bw[g][kt - 2] = cvt8(Wih + n * 256 + kt * 32 + q * 8);
    #pragma unroll
    for (int kt = 8; kt < 12; ++kt) bw[g][kt - 2] = cvt8(Whh + n * HD + (kt - 8) * 32 + q * 8);
    bias[g] = bih[n] + bhh[n];
  }

  const int sb   = 2 * w + (lane >> 5);         // batch row 0..15
  const int cimg = lane & 31;
  const int sig  = (cimg & 16) | ((cimg & 15) ^ (sb & 15));
  const size_t grow = (size_t)(bbase + sb) * T_SEQ * 256 + (size_t)sig * 8;
  unsigned short* b0 = &ybuf[0][0];
  unsigned short* b1 = &ybuf[1][0];
  unsigned short* b2 = &ybuf[2][0];

  int t = dir ? (T_SEQ - 1) : 0;
  const int dt = dir ? -1 : 1;

  float cst[4] = {0.f, 0.f, 0.f, 0.f};
  for (int i = tid; i < 2 * BT * HP; i += 512) (&h_buf[0][0])[i] = 0;
  gl_lds16(y0 + grow + (size_t)t * 256,        b0 + w * 512);   // tile 0
  gl_lds16(y0 + grow + (size_t)(t + dt) * 256, b1 + w * 512);   // tile 1
  __syncthreads();                                               // drains vmcnt

  f32x4 accP[4], accQ[4];
  ENC1_YPART(accP, b0)   // y0-partial for step 0

  for (int m = 0; m < T_SEQ / 2; ++m) {
    const int s0 = 2 * m;
    ENC1_BODY(s0,     0, 1, accP, accQ)
    ENC1_BODY(s0 + 1, 1, 0, accQ, accP)
  }
}

// ---------------------------------------------------------------------------
// Bridge: h_dec = h_enc @ brh_W.T + brh_b ; same for c with brc. Pure fp32.
// ---------------------------------------------------------------------------
__global__ void bridge_kernel(const float* __restrict__ ench0, const float* __restrict__ encc0,
                              const float* __restrict__ ench1, const float* __restrict__ encc1,
                              const float* __restrict__ brhW, const float* __restrict__ brhb,
                              const float* __restrict__ brcW, const float* __restrict__ brcb,
                              float* __restrict__ dech, float* __restrict__ decc)
{
  const int idx = blockIdx.x * 256 + threadIdx.x;   // 262144 total
  const int sel = idx >> 17;          // 0: h, 1: c
  const int l   = (idx >> 16) & 1;    // layer
  const int b   = (idx >> 7) & 511;
  const int j   = idx & 127;
  const float* W  = sel ? brcW : brhW;
  const float* bb = sel ? brcb : brhb;
  const float* s0 = sel ? (l ? encc1 : encc0) : (l ? ench1 : ench0);
  float a = bb[j];
  for (int k = 0; k < 128; ++k) a += W[j * 256 + k] * s0[b * 128 + k];
  for (int k = 0; k < 128; ++k) a += W[j * 256 + 128 + k] * s0[(512 + b) * 128 + k];
  float* dst = sel ? decc : dech;
  dst[(l * 512 + b) * 128 + j] = a;
}

// ---------------------------------------------------------------------------
// Decoder: EXACT R4 structure (fastest measured: ~874 us) + fast tanh only.
// 512 thr, W0hh/W1ih k0..63 in LDS, rest in regs; 2 barriers/step;
// out-proj redundant on all waves + shfl xin feedback.
// ---------------------------------------------------------------------------
__global__ __launch_bounds__(512, 2)
void decoder_kernel(const float* __restrict__ dech, const float* __restrict__ decc,
                    const float* __restrict__ W0ih, const float* __restrict__ W0hh,
                    const float* __restrict__ b0ih, const float* __restrict__ b0hh,
                    const float* __restrict__ W1ih, const float* __restrict__ W1hh,
                    const float* __restrict__ b1ih, const float* __restrict__ b1hh,
                    const float* __restrict__ outW, const float* __restrict__ outb,
                    const float* __restrict__ stok,
                    float* __restrict__ out)
{
  __shared__ __align__(16) unsigned short w0lds[GD * WLP];   // W0hh k0..63
  __shared__ __align__(16) unsigned short w1lds[GD * WLP];   // W1ih k0..63
  __shared__ __align__(16) unsigned short h0_buf[2][BT * HP];
  __shared__ __align__(16) unsigned short h1_buf[2][BT * HP];

  const int tid  = threadIdx.x;
  const int lane = tid & 63;
  const int w    = tid >> 6;      // 0..7
  const int l15  = lane & 15;
  const int q    = lane >> 4;
  const int bbase = blockIdx.x * BT;

  for (int i = tid; i < GD * 8; i += 512) {
    const int n = i >> 3, c8 = i & 7;
    *reinterpret_cast<bf16x8*>(&w0lds[n * WLP + c8 * 8]) = cvt8(W0hh + n * HD + c8 * 8);
    *reinterpret_cast<bf16x8*>(&w1lds[n * WLP + c8 * 8]) = cvt8(W1ih + n * HD + c8 * 8);
  }

  bf16x8 bw0[4][2];    // W0hh k64..127
  bf16x8 bw1[4][6];    // W1ih k64..127 (2) + W1hh k0..127 (4)
  float  xw0[4][3], bias0[4], bias1[4];
  int    nofs[4];
  #pragma unroll
  for (int g = 0; g < 4; ++g) {
    const int n = g * 128 + w * 16 + l15;
    nofs[g] = n * WLP;
    #pragma unroll
    for (int kt = 2; kt < 4; ++kt) {
      bw0[g][kt - 2] = cvt8(W0hh + n * HD + kt * 32 + q * 8);
      bw1[g][kt - 2] = cvt8(W1ih + n * HD + kt * 32 + q * 8);
    }
    #pragma unroll
    for (int kt = 4; kt < 8; ++kt)
      bw1[g][kt - 2] = cvt8(W1hh + n * HD + (kt - 4) * 32 + q * 8);
    #pragma unroll
    for (int k = 0; k < 3; ++k) xw0[g][k] = W0ih[n * 3 + k];
    bias0[g] = b0ih[n] + b0hh[n];
    bias1[g] = b1ih[n] + b1hh[n];
  }

  // out-projection fragments on ALL waves (redundant compute kills a barrier)
  bf16x8 owf[4];
  float outb_s = 0.f;
  {
    bf16x8 z;
    #pragma unroll
    for (int i = 0; i < 8; ++i) z[i] = 0;
    #pragma unroll
    for (int kt = 0; kt < 4; ++kt) owf[kt] = z;
    if (l15 < 3) {
      #pragma unroll
      for (int kt = 0; kt < 4; ++kt) owf[kt] = cvt8(outW + l15 * HD + kt * 32 + q * 8);
      outb_s = outb[l15];
    }
  }

  float c0[4], c1[4];
  #pragma unroll
  for (int r = 0; r < 4; ++r) {
    const int b   = bbase + q * 4 + r;
    const int cix = w * 16 + l15;
    c0[r] = decc[b * HD + cix];
    c1[r] = decc[(NB + b) * HD + cix];
  }
  for (int i = tid; i < BT * HD; i += 512) {
    const int b = i >> 7, cix = i & 127;
    h0_buf[0][b * HP + cix] = f2bf(dech[(bbase + b) * HD + cix]);
    h1_buf[0][b * HP + cix] = f2bf(dech[(NB + bbase + b) * HD + cix]);
  }
  float xr[4][3];
  {
    const float s0 = stok[0], s1 = stok[1], s2 = stok[2];
    #pragma unroll
    for (int r = 0; r < 4; ++r) { xr[r][0] = s0; xr[r][1] = s1; xr[r][2] = s2; }
  }
  __syncthreads();

  for (int s = 0; s < HORZ; ++s) {
    const int cur = s & 1, nxt = cur ^ 1;

    // ---- cell 0 ----
    f32x4 acc[4];
    #pragma unroll
    for (int g = 0; g < 4; ++g)
      #pragma unroll
      for (int r = 0; r < 4; ++r)
        acc[g][r] = bias0[g] + xw0[g][0] * xr[r][0] + xw0[g][1] * xr[r][1] + xw0[g][2] * xr[r][2];
    #pragma unroll
    for (int kt = 0; kt < 2; ++kt) {
      const bf16x8 af = *reinterpret_cast<const bf16x8*>(&h0_buf[cur][l15 * HP + kt * 32 + q * 8]);
      #pragma unroll
      for (int g = 0; g < 4; ++g) {
        const bf16x8 bl = *reinterpret_cast<const bf16x8*>(&w0lds[nofs[g] + kt * 32 + q * 8]);
        acc[g] = MFMA16(af, bl, acc[g]);
      }
    }
    #pragma unroll
    for (int kt = 2; kt < 4; ++kt) {
      const bf16x8 af = *reinterpret_cast<const bf16x8*>(&h0_buf[cur][l15 * HP + kt * 32 + q * 8]);
      #pragma unroll
      for (int g = 0; g < 4; ++g) acc[g] = MFMA16(af, bw0[g][kt - 2], acc[g]);
    }
    #pragma unroll
    for (int r = 0; r < 4; ++r) {
      const float i_ = acc[0][r], f_ = acc[1][r], g_ = acc[2][r], o_ = acc[3][r];
      const float c_ = sigm(f_) * c0[r] + sigm(i_) * tanh_(g_);
      c0[r] = c_;
      const float h_ = sigm(o_) * tanh_(c_);
      h0_buf[nxt][(q * 4 + r) * HP + w * 16 + l15] = f2bf(h_);
    }
    __syncthreads();   // barrier A: h0 new visible

    // ---- cell 1 ----
    #pragma unroll
    for (int g = 0; g < 4; ++g) {
      acc[g][0] = bias1[g]; acc[g][1] = bias1[g];
      acc[g][2] = bias1[g]; acc[g][3] = bias1[g];
    }
    #pragma unroll
    for (int kt = 0; kt < 2; ++kt) {
      const bf16x8 af = *reinterpret_cast<const bf16x8*>(&h0_buf[nxt][l15 * HP + kt * 32 + q * 8]);
      #pragma unroll
      for (int g = 0; g < 4; ++g) {
        const bf16x8 bl = *reinterpret_cast<const bf16x8*>(&w1lds[nofs[g] + kt * 32 + q * 8]);
        acc[g] = MFMA16(af, bl, acc[g]);
      }
    }
    #pragma unroll
    for (int kt = 2; kt < 4; ++kt) {
      const bf16x8 af = *reinterpret_cast<const bf16x8*>(&h0_buf[nxt][l15 * HP + kt * 32 + q * 8]);
      #pragma unroll
      for (int g = 0; g < 4; ++g) acc[g] = MFMA16(af, bw1[g][kt - 2], acc[g]);
    }
    #pragma unroll
    for (int kt = 4; kt < 8; ++kt) {
      const bf16x8 af = *reinterpret_cast<const bf16x8*>(&h1_buf[cur][l15 * HP + (kt - 4) * 32 + q * 8]);
      #pragma unroll
      for (int g = 0; g < 4; ++g) acc[g] = MFMA16(af, bw1[g][kt - 2], acc[g]);
    }
    #pragma unroll
    for (int r = 0; r < 4; ++r) {
      const float i_ = acc[0][r], f_ = acc[1][r], g_ = acc[2][r], o_ = acc[3][r];
      const float c_ = sigm(f_) * c1[r] + sigm(i_) * tanh_(g_);
      c1[r] = c_;
      const float h_ = sigm(o_) * tanh_(c_);
      h1_buf[nxt][(q * 4 + r) * HP + w * 16 + l15] = f2bf(h_);
    }
    __syncthreads();   // barrier B: h1 new visible

    // ---- out projection (all waves, redundant) + shfl feedback ----
    f32x4 p = {0.f, 0.f, 0.f, 0.f};
    #pragma unroll
    for (int kt = 0; kt < 4; ++kt) {
      const bf16x8 af = *reinterpret_cast<const bf16x8*>(&h1_buf[nxt][l15 * HP + kt * 32 + q * 8]);
      p = MFMA16(af, owf[kt], p);
    }
    float pb[4];
    #pragma unroll
    for (int r = 0; r < 4; ++r) pb[r] = p[r] + outb_s;
    if (w == 0 && l15 < 3) {
      #pragma unroll
      for (int r = 0; r < 4; ++r)
        out[((size_t)(bbase + q * 4 + r) * HORZ + s) * 3 + l15] = pb[r];
    }
    #pragma unroll
    for (int r = 0; r < 4; ++r)
      #pragma unroll
      for (int c = 0; c < 3; ++c)
        xr[r][c] = __shfl(pb[r], (q << 4) + c, 64);
    // no barrier: next step writes touch opposite buffers only
  }
}

// ---------------------------------------------------------------------------
extern "C" void kernel_launch(void* const* d_in, const int* in_sizes, int n_in,
                              void* d_out, int out_size, void* d_ws, size_t ws_size,
                              hipStream_t stream)
{
  (void)in_sizes; (void)n_in; (void)out_size; (void)ws_size;
  const float* x      = (const float*)d_in[0];
  const float* e0fWih = (const float*)d_in[1];
  const float* e0fWhh = (const float*)d_in[2];
  const float* e0fbih = (const float*)d_in[3];
  const float* e0fbhh = (const float*)d_in[4];
  const float* e0bWih = (const float*)d_in[5];
  const float* e0bWhh = (const float*)d_in[6];
  const float* e0bbih = (const float*)d_in[7];
  const float* e0bbhh = (const float*)d_in[8];
  const float* e1fWih = (const float*)d_in[9];
  const float* e1fWhh = (const float*)d_in[10];
  const float* e1fbih = (const float*)d_in[11];
  const float* e1fbhh = (const float*)d_in[12];
  const float* e1bWih = (const float*)d_in[13];
  const float* e1bWhh = (const float*)d_in[14];
  const float* e1bbih = (const float*)d_in[15];
  const float* e1bbhh = (const float*)d_in[16];
  const float* brhW   = (const float*)d_in[17];
  const float* brhb   = (const float*)d_in[18];
  const float* brcW   = (const float*)d_in[19];
  const float* brcb   = (const float*)d_in[20];
  const float* d0Wih  = (const float*)d_in[21];
  const float* d0Whh  = (const float*)d_in[22];
  const float* d0bih  = (const float*)d_in[23];
  const float* d0bhh  = (const float*)d_in[24];
  const float* d1Wih  = (const float*)d_in[25];
  const float* d1Whh  = (const float*)d_in[26];
  const float* d1bih  = (const float*)d_in[27];
  const float* d1bhh  = (const float*)d_in[28];
  const float* outW   = (const float*)d_in[29];
  const float* outb   = (const float*)d_in[30];
  const float* stok   = (const float*)d_in[31];

  char* ws = (char*)d_ws;
  unsigned short* y0 = (unsigned short*)ws;                        // internal bf16
  size_t off = (size_t)NB * T_SEQ * 256 * sizeof(unsigned short);  // 188.7 MB
  const size_t blk = (size_t)2 * NB * HD * sizeof(float);          // 512 KB each
  float* ench0 = (float*)(ws + off); off += blk;
  float* encc0 = (float*)(ws + off); off += blk;
  float* ench1 = (float*)(ws + off); off += blk;
  float* encc1 = (float*)(ws + off); off += blk;
  float* dech  = (float*)(ws + off); off += blk;
  float* decc  = (float*)(ws + off); off += blk;

  enc_layer0_kernel<<<dim3(64), dim3(512), 0, stream>>>(
      x, e0fWih, e0fWhh, e0fbih, e0fbhh, e0bWih, e0bWhh, e0bbih, e0bbhh,
      y0, ench0, encc0);
  enc_layer1_kernel<<<dim3(64), dim3(512), 0, stream>>>(
      y0, e1fWih, e1fWhh, e1fbih, e1fbhh, e1bWih, e1bWhh, e1bbih, e1bbhh,
      ench1, encc1);
  bridge_kernel<<<dim3(1024), dim3(256), 0, stream>>>(
      ench0, encc0, ench1, encc1, brhW, brhb, brcW, brcb, dech, decc);
  decoder_kernel<<<dim3(32), dim3(512), 0, stream>>>(
      dech, decc, d0Wih, d0Whh, d0bih, d0bhh, d1Wih, d1Whh, d1bih, d1bhh,
      outW, outb, stok, (float*)d_out);
}